// Round 12
// baseline (240.870 us; speedup 1.0000x reference)
//
#include <hip/hip_runtime.h>

#define DELTA 1e-6f

// sizes: b=64, m=1024, w=64, r=4, d=512, iface=471
#define NB 64
#define NM 1024
#define NW 64
#define NR 4
#define ND 512
#define NIF 471

typedef unsigned long long ull;

__device__ __forceinline__ float sigmoidf_(float x){ return 1.0f/(1.0f+expf(-x)); }
__device__ __forceinline__ float softplusf_(float x){ return fmaxf(x,0.0f) + log1pf(expf(-fabsf(x))); }

__device__ __forceinline__ float waveSum(float v){
  #pragma unroll
  for(int o=32;o>0;o>>=1) v += __shfl_down(v,o,64);
  return v;
}
__device__ __forceinline__ float waveMax(float v){
  #pragma unroll
  for(int o=32;o>0;o>>=1) v = fmaxf(v, __shfl_down(v,o,64));
  return v;
}
__device__ __forceinline__ ull shflxor64(ull k, int m){
  unsigned lo = (unsigned)(k & 0xffffffffu), hi = (unsigned)(k>>32);
  lo = (unsigned)__shfl_xor((int)lo, m, 64);
  hi = (unsigned)__shfl_xor((int)hi, m, 64);
  return ((ull)hi<<32)|lo;
}

// ---------------- K0: zero the output (k_readb accumulates into it) ----------------
__global__ __launch_bounds__(256) void k_zero(float4* __restrict__ p, int n4){
  int i = blockIdx.x*256 + threadIdx.x;
  if (i < n4) p[i] = make_float4(0.f,0.f,0.f,0.f);
}

// ---------------- K1: iface = xi @ W + bW (128 blocks) ----------------
__global__ __launch_bounds__(256) void k_iface(const float* __restrict__ xi,
                                               const float* __restrict__ Wm,
                                               const float* __restrict__ bW,
                                               float* __restrict__ iface){
  int b = blockIdx.x, half = blockIdx.y;
  __shared__ float xs[ND];
  for(int k=threadIdx.x;k<ND;k+=256) xs[k]=xi[b*ND+k];
  __syncthreads();
  int c = half*236 + threadIdx.x;
  int cend = half ? NIF : 236;
  if (c < cend){
    float acc = bW[c];
    #pragma unroll 4
    for(int k=0;k<ND;k++) acc = fmaf(xs[k], Wm[k*NIF+c], acc);
    iface[b*NIF+c]=acc;
  }
}

// ---------------- K1b: full-GPU pass over mem for write-content dot/nrm + usage ----------------
__global__ __launch_bounds__(256) void k_wcos(
    const float* __restrict__ iface, const float* __restrict__ mem,
    const float* __restrict__ rw_old, const float* __restrict__ ww_old,
    const float* __restrict__ uv,
    float* __restrict__ uu, float* __restrict__ wcd, float* __restrict__ wcn){
  int b = blockIdx.y;
  int j = blockIdx.x*256 + threadIdx.x;
  __shared__ float wkey[NW];
  const float* ifb = iface + b*NIF;
  if (threadIdx.x < NW) wkey[threadIdx.x] = ifb[260+threadIdx.x];
  __syncthreads();
  float fg0=sigmoidf_(ifb[453]), fg1=sigmoidf_(ifb[454]);
  float fg2=sigmoidf_(ifb[455]), fg3=sigmoidf_(ifb[456]);
  float u0  = uv[b*NM+j];
  float wwo = ww_old[b*NM+j];
  float usage = u0 + (1.0f-u0)*wwo;
  float psi = (1.0f - fg0*rw_old[(b*NR+0)*NM+j])
            * (1.0f - fg1*rw_old[(b*NR+1)*NM+j])
            * (1.0f - fg2*rw_old[(b*NR+2)*NM+j])
            * (1.0f - fg3*rw_old[(b*NR+3)*NM+j]);
  usage *= psi;
  uu[b*NM+j] = DELTA + (1.0f-DELTA)*usage;
  float dot=0.0f, nrm=0.0f;
  const float4* mrow4 = (const float4*)(mem + ((size_t)b*NM + j)*NW);
  #pragma unroll 4
  for(int k=0;k<16;k++){
    float4 mv = mrow4[k];
    const float* wk = wkey + k*4;
    dot = fmaf(mv.x,wk[0],dot); dot = fmaf(mv.y,wk[1],dot);
    dot = fmaf(mv.z,wk[2],dot); dot = fmaf(mv.w,wk[3],dot);
    nrm = fmaf(mv.x,mv.x,nrm); nrm = fmaf(mv.y,mv.y,nrm);
    nrm = fmaf(mv.z,mv.z,nrm); nrm = fmaf(mv.w,mv.w,nrm);
  }
  wcd[b*NM+j]=dot; wcn[b*NM+j]=nrm;
}

// ---------------- K2: softmax + bitonic sort + cumprod + new_write_w ----------------
__global__ __launch_bounds__(1024) void k_write2(
    const float* __restrict__ iface, const float* __restrict__ uu,
    const float* __restrict__ wcd, const float* __restrict__ wcn,
    float* __restrict__ wwp){
  int b = blockIdx.x; int tid = threadIdx.x;
  int lane = tid & 63, wv = tid >> 6;
  __shared__ float wkey[NW];
  __shared__ ull skA[NM];
  __shared__ ull skB[NM];
  __shared__ float fb2[NM];
  __shared__ float red[17];
  __shared__ float s_wp[16], s_wp2[16];
  const float* ifb = iface + b*NIF;
  if (tid < NW) wkey[tid] = ifb[260+tid];
  __syncthreads();
  float sw = softplusf_(1.0f + fmaxf(ifb[324],0.0f));
  float ag = sigmoidf_(ifb[457]);
  float wg = sigmoidf_(ifb[458]);
  float kn=0.0f;
  for(int k=0;k<NW;k++){ float t=wkey[k]; kn += t*t; }
  kn = sqrtf(kn);
  float logit = sw * wcd[b*NM+tid] / ((sqrtf(wcn[b*NM+tid])+DELTA)*(kn+DELTA));
  float m1 = waveMax(logit); if(lane==0) red[wv]=m1; __syncthreads();
  if(tid==0){ float mm=red[0]; for(int i=1;i<16;i++) mm=fmaxf(mm,red[i]); red[16]=mm; } __syncthreads();
  float e = expf(logit - red[16]);
  float s1 = waveSum(e); if(lane==0) red[wv]=s1; __syncthreads();
  if(tid==0){ float ss=0; for(int i=0;i<16;i++) ss+=red[i]; red[16]=ss; } __syncthreads();
  float wcw = e/red[16];
  // ---- bitonic sort of (u, idx): strides<64 via shfl, >=64 via ping-pong LDS ----
  float u = uu[b*NM+tid];
  ull k = ((ull)__float_as_uint(u) << 32) | (unsigned)tid;
  bool useA = true;
  for (int k2=2; k2<=NM; k2<<=1){
    for (int jj=k2>>1; jj>0; jj>>=1){
      ull p;
      if (jj >= 64){
        ull* buf = useA ? skA : skB;
        buf[tid] = k;
        __syncthreads();
        p = buf[tid^jj];
        useA = !useA;
      } else {
        p = shflxor64(k, jj);
      }
      bool lower = (tid & jj) == 0;
      bool asc   = (tid & k2) == 0;
      bool takeMin = (lower == asc);
      k = takeMin ? (k<p ? k : p) : (k>p ? k : p);
    }
  }
  float su = __uint_as_float((unsigned)(k>>32));
  int phi  = (int)(k & 0xffffffffu);
  // ---- inclusive cumprod: wave scan + cross-wave prefix ----
  float sc = su;
  #pragma unroll
  for (int off=1; off<64; off<<=1){
    float t = __shfl_up(sc, off, 64);
    if (lane >= off) sc *= t;
  }
  if (lane==63) s_wp[wv] = sc;
  __syncthreads();
  if (tid==0){
    float p=1.0f;
    for (int w=0;w<16;w++){ float t=s_wp[w]; s_wp2[w]=p; p*=t; }
  }
  __syncthreads();
  float P = sc * s_wp2[wv];
  float salloc = (1.0f - su)*P;
  fb2[phi] = salloc;
  __syncthreads();
  float alloc = fb2[tid];
  wwp[b*NM+tid] = wg*(ag*alloc + (1.0f-ag)*wcw);
}

// ---------------- K3: one streaming pass over L (LDS-staged, 2-rows-per-lane phase R) ----------------
// ROUND 12 NOTE: launched TWICE this round as a pure diagnostic — k_link8 is a pure
// function of its inputs (all outputs unconditional stores), so the second launch is
// bit-identical; total_12 - total_11 = dur(k_link8) exactly. It has been invisible in
// top-5 since round 6 (1GB harness poison fills occupy all slots at ~152-159us).
__global__ __launch_bounds__(256) void k_link8(
    const float* __restrict__ link, const float* __restrict__ rw,
    const float* __restrict__ wwp,
    float4* __restrict__ RFp, float* __restrict__ C2p, float* __restrict__ C3p,
    float* __restrict__ ldiag){
  int cx = blockIdx.x, ry = blockIdx.y, b = blockIdx.z;
  int tid = threadIdx.x, lane = tid&63, wv = tid>>6;
  __shared__ float4 s_L4[32*64];   // 32KB
  __shared__ float4 s_gcol4[256];  // 4KB {g0..g3} per col
  __shared__ float  s_mwc[256];    // 1KB: 1-ww[col]
  __shared__ float4 s_grow4[32];
  __shared__ float  s_wwr[32];
  __shared__ float4 s_rfp4[128];
  const float* Lb = link + ((size_t)b<<20);
  int colbase = cx*256, rowbase = ry*256;
  {
    float g0 = rw[(b*NR+0)*NM + colbase + tid];
    float g1 = rw[(b*NR+1)*NM + colbase + tid];
    float g2 = rw[(b*NR+2)*NM + colbase + tid];
    float g3 = rw[(b*NR+3)*NM + colbase + tid];
    s_gcol4[tid] = make_float4(g0,g1,g2,g3);
    s_mwc[tid] = 1.0f - wwp[b*NM + colbase + tid];
  }
  float c2a[NR][4], c3a[NR][4];
  #pragma unroll
  for(int r=0;r<NR;r++){
    #pragma unroll
    for(int e=0;e<4;e++){ c2a[r][e]=0.0f; c3a[r][e]=0.0f; }
  }
  for (int ch=0; ch<8; ++ch){
    int rb = rowbase + ch*32;
    if (tid < 128) ((float*)s_grow4)[tid] = rw[(b*NR+(tid&3))*NM + rb + (tid>>2)];
    if (tid < 32)  s_wwr[tid] = wwp[b*NM + rb + tid];
    #pragma unroll
    for (int jq=0;jq<8;jq++){
      int rl = wv + 4*jq;
      float4 lv = *(const float4*)(Lb + (size_t)(rb+rl)*NM + colbase + lane*4);
      s_L4[rl*64 + (lane ^ ((rl>>1)&7))] = lv;
    }
    __syncthreads();
    // diag export (cx==ry blocks contain the diagonal of this row range)
    if (cx == ry && tid < 32){
      int coff = ch*32 + tid;
      float4 v = s_L4[tid*64 + ((coff>>2) ^ ((tid>>1)&7))];
      float d = (coff&1) ? ((coff&2)? v.w : v.y) : ((coff&2)? v.z : v.x);
      ldiag[b*NM + rb + tid] = d;
    }
    // ---- phase R: lane owns rows {2i,2i+1}, 16 cols (cg) ----
    {
      int i5 = lane & 15, cg = lane >> 4;
      int rl0 = 2*i5;
      int sz = i5 & 7;               // (rl0>>1)&7, same for both rows
      float wwj0 = s_wwr[rl0], wwj1 = s_wwr[rl0+1];
      float rf0[4] = {0,0,0,0}, rf1[4] = {0,0,0,0};
      #pragma unroll
      for (int q=0;q<4;q++){
        int cq = wv*16 + cg*4 + q;
        float4 mw  = ((const float4*)s_mwc)[cq];
        float4 lv0 = s_L4[rl0*64 + (cq ^ sz)];
        float4 lv1 = s_L4[(rl0+1)*64 + (cq ^ sz)];
        float le0[4]={lv0.x,lv0.y,lv0.z,lv0.w};
        float le1[4]={lv1.x,lv1.y,lv1.z,lv1.w};
        float mv[4]={mw.x,mw.y,mw.z,mw.w};
        #pragma unroll
        for (int e=0;e<4;e++){
          float4 gv = s_gcol4[cq*4+e];
          float lt0 = le0[e]*(mv[e]-wwj0);
          float lt1 = le1[e]*(mv[e]-wwj1);
          rf0[0]=fmaf(lt0,gv.x,rf0[0]); rf0[1]=fmaf(lt0,gv.y,rf0[1]);
          rf0[2]=fmaf(lt0,gv.z,rf0[2]); rf0[3]=fmaf(lt0,gv.w,rf0[3]);
          rf1[0]=fmaf(lt1,gv.x,rf1[0]); rf1[1]=fmaf(lt1,gv.y,rf1[1]);
          rf1[2]=fmaf(lt1,gv.z,rf1[2]); rf1[3]=fmaf(lt1,gv.w,rf1[3]);
        }
      }
      // sum the 4 col-groups (lanes i, i+16, i+32, i+48)
      #pragma unroll
      for (int r=0;r<NR;r++){
        rf0[r] += __shfl_xor(rf0[r], 16, 64);
        rf0[r] += __shfl_xor(rf0[r], 32, 64);
        rf1[r] += __shfl_xor(rf1[r], 16, 64);
        rf1[r] += __shfl_xor(rf1[r], 32, 64);
      }
      if (cg == 0){
        s_rfp4[wv*32 + rl0]     = make_float4(rf0[0],rf0[1],rf0[2],rf0[3]);
        s_rfp4[wv*32 + rl0 + 1] = make_float4(rf1[0],rf1[1],rf1[2],rf1[3]);
      }
    }
    // ---- phase C: wave covers 8 rows, lane owns 4 cols ----
    #pragma unroll 2
    for (int ri=0; ri<8; ri++){
      int row = wv*8 + ri;
      float4 lv = s_L4[row*64 + (lane ^ ((row>>1)&7))];
      float4 gg = s_grow4[row];
      float wwr = s_wwr[row];
      float le[4] = {lv.x,lv.y,lv.z,lv.w};
      float ggv[4] = {gg.x,gg.y,gg.z,gg.w};
      float ggw[4];
      #pragma unroll
      for (int r=0;r<NR;r++) ggw[r] = ggv[r]*wwr;
      #pragma unroll
      for (int e=0;e<4;e++){
        #pragma unroll
        for (int r=0;r<NR;r++){
          c2a[r][e] = fmaf(le[e], ggv[r], c2a[r][e]);
          c3a[r][e] = fmaf(le[e], ggw[r], c3a[r][e]);
        }
      }
    }
    __syncthreads();
    if (tid < 128){
      int row = tid>>2, r = tid&3;
      float s = ((const float*)&s_rfp4[0*32+row])[r] + ((const float*)&s_rfp4[1*32+row])[r]
              + ((const float*)&s_rfp4[2*32+row])[r] + ((const float*)&s_rfp4[3*32+row])[r];
      ((float*)RFp)[((size_t)cx<<18) + (b*NM + rb + row)*4 + r] = s;
    }
    __syncthreads();
  }
  // ---- c2/c3 cross-wave combine (reuse s_L4), plain float4 stores to own slice ----
  float4* s_comb = s_L4;
  #pragma unroll
  for (int r=0;r<NR;r++){
    s_comb[tid*8 + r]     = make_float4(c2a[r][0],c2a[r][1],c2a[r][2],c2a[r][3]);
    s_comb[tid*8 + 4 + r] = make_float4(c3a[r][0],c3a[r][1],c3a[r][2],c3a[r][3]);
  }
  __syncthreads();
  for (int t=tid; t<512; t+=256){
    int lc = t>>3, q = t&7;
    float4 a = s_comb[(0*64+lc)*8+q];
    float4 bb= s_comb[(1*64+lc)*8+q];
    float4 c = s_comb[(2*64+lc)*8+q];
    float4 d = s_comb[(3*64+lc)*8+q];
    float4 s = make_float4(a.x+bb.x+c.x+d.x, a.y+bb.y+c.y+d.y, a.z+bb.z+c.z+d.z, a.w+bb.w+c.w+d.w);
    float* dst = (q<4) ? &C2p[((size_t)ry<<18) + (b*NR+q)*NM + colbase + lc*4]
                       : &C3p[((size_t)ry<<18) + (b*NR+(q-4))*NM + colbase + lc*4];
    *(float4*)dst = s;
  }
}

// ---------------- K4a: full-GPU pass over mem for read-content dots/nrm ----------------
__global__ __launch_bounds__(256) void k_rdots(
    const float* __restrict__ iface, const float* __restrict__ mem,
    const float* __restrict__ wwp, float* __restrict__ dots){
  int b = blockIdx.y;
  int j = blockIdx.x*256 + threadIdx.x;
  __shared__ float keys[NR][NW];
  __shared__ float er[NW], wvec[NW];
  const float* ifb = iface + b*NIF;
  { int r=threadIdx.x>>6, kk=threadIdx.x&63; keys[r][kk] = ifb[r*NW+kk]; }
  if (threadIdx.x < 64) er[threadIdx.x] = sigmoidf_(ifb[325+threadIdx.x]);
  else if (threadIdx.x < 128) wvec[threadIdx.x-64] = ifb[389+threadIdx.x-64];
  __syncthreads();
  float wwj = wwp[b*NM+j];
  const float* mrow = mem + ((size_t)b*NM+j)*NW;
  float dt[NR]={0,0,0,0}; float nrm=0.0f;
  for(int k=0;k<NW;k++){
    float nmv = fmaf(mrow[k], (1.0f - wwj*er[k]), wwj*wvec[k]);
    nrm = fmaf(nmv,nmv,nrm);
    #pragma unroll
    for(int r=0;r<NR;r++) dt[r] = fmaf(nmv, keys[r][k], dt[r]);
  }
  #pragma unroll
  for(int r=0;r<NR;r++) dots[(b*5+r)*NM + j] = dt[r];
  dots[(b*5+4)*NM + j] = nrm;
}

// ---------------- K4b: Pr/Kr + read softmax + fwd/bwd finalize -> nrw (sums partial slices inline) ----------------
__global__ __launch_bounds__(1024) void k_rmid(
    const float* __restrict__ iface, const float* __restrict__ prec,
    const float* __restrict__ rw_old, const float* __restrict__ wwp,
    const float* __restrict__ dots, const float* __restrict__ ldiag,
    const float4* __restrict__ RFp4, const float* __restrict__ C2p, const float* __restrict__ C3p,
    float* __restrict__ nrwg){
  int b = blockIdx.x; int tid = threadIdx.x; int lane=tid&63, wv=tid>>6;
  __shared__ float s_pk[16][8];
  __shared__ float scal[16];   // [0..3]=Pr, [4..7]=Kr, [8..11]=keynorm, [12..15]=strength
  __shared__ float smax[NR], ssum[NR];
  __shared__ float rm[NR][3];
  const float* ifb = iface + b*NIF;
  if (tid == 0){
    for(int mo=0;mo<3;mo++){
      float x0=ifb[458+0*3+mo], x1=ifb[458+1*3+mo], x2=ifb[458+2*3+mo], x3=ifb[458+3*3+mo];
      float mx = fmaxf(fmaxf(x0,x1),fmaxf(x2,x3));
      float e0=expf(x0-mx),e1=expf(x1-mx),e2=expf(x2-mx),e3=expf(x3-mx);
      float s=e0+e1+e2+e3;
      rm[0][mo]=e0/s; rm[1][mo]=e1/s; rm[2][mo]=e2/s; rm[3][mo]=e3/s;
    }
  }
  if (tid >= 320 && tid < 324){
    int r = tid-320;
    float knv=0;
    for(int k=0;k<NW;k++){ float t=ifb[r*NW+k]; knv += t*t; }
    scal[8+r]  = sqrtf(knv);
    scal[12+r] = softplusf_(1.0f + fmaxf(ifb[256+r],0.0f));
  }
  __syncthreads();
  int j = tid;
  float pj  = prec[b*NM+j];
  float wwj = wwp[b*NM+j];
  float rwv[NR];
  #pragma unroll
  for(int r=0;r<NR;r++) rwv[r]=rw_old[(b*NR+r)*NM+j];
  {
    float v8[8];
    #pragma unroll
    for(int r=0;r<NR;r++){ v8[r] = pj*rwv[r]; v8[4+r] = wwj*rwv[r]; }
    #pragma unroll
    for(int q=0;q<8;q++){
      float s = waveSum(v8[q]);
      if(lane==0) s_pk[wv][q]=s;
    }
    __syncthreads();
    if (tid < 8){
      float ss=0;
      for(int w=0;w<16;w++) ss += s_pk[w][tid];
      scal[tid]=ss;
    }
    __syncthreads();
  }
  float dt[NR];
  #pragma unroll
  for(int r=0;r<NR;r++) dt[r] = dots[(b*5+r)*NM + j];
  float nrm = dots[(b*5+4)*NM + j];
  float inv = 1.0f/(sqrtf(nrm)+DELTA);
  float logit[NR], ce[NR], cw[NR];
  #pragma unroll
  for(int r=0;r<NR;r++) logit[r] = scal[12+r]*dt[r]*inv/(scal[8+r]+DELTA);
  #pragma unroll
  for(int r=0;r<NR;r++){
    float m1 = waveMax(logit[r]);
    if(lane==0) s_pk[wv][r]=m1;
  }
  __syncthreads();
  if (tid < NR){
    float mm=s_pk[0][tid];
    for(int w=1;w<16;w++) mm=fmaxf(mm,s_pk[w][tid]);
    smax[tid]=mm;
  }
  __syncthreads();
  #pragma unroll
  for(int r=0;r<NR;r++){
    ce[r] = expf(logit[r]-smax[r]);
    float s1 = waveSum(ce[r]);
    if(lane==0) s_pk[wv][r]=s1;
  }
  __syncthreads();
  if (tid < NR){
    float ss=0;
    for(int w=0;w<16;w++) ss += s_pk[w][tid];
    ssum[tid]=ss;
  }
  __syncthreads();
  #pragma unroll
  for(int r=0;r<NR;r++) cw[r] = ce[r]/ssum[r];
  float Ljj = ldiag[b*NM+j];
  // inline combine of the 4 partial slices
  float4 Fa = RFp4[(0<<16) + b*NM + j];
  float4 Fb = RFp4[(1<<16) + b*NM + j];
  float4 Fc = RFp4[(2<<16) + b*NM + j];
  float4 Fd = RFp4[(3<<16) + b*NM + j];
  float Fr[4] = {Fa.x+Fb.x+Fc.x+Fd.x, Fa.y+Fb.y+Fc.y+Fd.y,
                 Fa.z+Fb.z+Fc.z+Fd.z, Fa.w+Fb.w+Fc.w+Fd.w};
  #pragma unroll
  for(int r=0;r<NR;r++){
    int idx = (b*NR+r)*NM + j;
    float cc2 = C2p[idx] + C2p[262144+idx] + C2p[524288+idx] + C2p[786432+idx];
    float cc3 = C3p[idx] + C3p[262144+idx] + C3p[524288+idx] + C3p[786432+idx];
    float F   = Fr[r];
    float grj = rwv[r];
    float fwd = F - Ljj*grj*(1.0f-2.0f*wwj) + wwj*(scal[r] - pj*grj);
    float bwd = (cc2 - cc3) - Ljj*grj*(1.0f-wwj) - wwj*(cc2 - Ljj*grj) + pj*(scal[4+r] - wwj*grj);
    nrwg[(b*NR+r)*NM+j] = rm[r][0]*bwd + rm[r][1]*fwd + rm[r][2]*cw[r];
  }
}

// ---------------- K4c: read_vectors = nrw @ new_memory, 256-block partial matmul ----------------
__global__ __launch_bounds__(256) void k_readb(
    const float* __restrict__ iface, const float* __restrict__ mem,
    const float* __restrict__ wwp, const float* __restrict__ nrwg,
    float* __restrict__ out){
  int jt = blockIdx.x, b = blockIdx.y;
  int tid = threadIdx.x, lane = tid&63, wv = tid>>6;
  __shared__ float s_nrw[NR][256];
  __shared__ float s_ww[256];
  __shared__ float s_er[NW], s_wv[NW];
  __shared__ float s_acc[4][NR][NW];
  const float* ifb = iface + b*NIF;
  int j0 = jt*256;
  #pragma unroll
  for(int r=0;r<NR;r++) s_nrw[r][tid] = nrwg[(b*NR+r)*NM + j0+tid];
  s_ww[tid] = wwp[b*NM + j0+tid];
  if (tid < 64) s_er[tid] = sigmoidf_(ifb[325+tid]);
  else if (tid < 128) s_wv[tid-64] = ifb[389+tid-64];
  __syncthreads();
  int w = lane;
  float erw = s_er[w], wvw = s_wv[w];
  float acc[NR]={0,0,0,0};
  for(int jj=0;jj<64;jj++){
    int jl = wv*64+jj;
    float wwr = s_ww[jl];
    float nmv = fmaf(mem[((size_t)b*NM + j0+jl)*NW + w], (1.0f - wwr*erw), wwr*wvw);
    #pragma unroll
    for(int r=0;r<NR;r++) acc[r] = fmaf(s_nrw[r][jl], nmv, acc[r]);
  }
  #pragma unroll
  for(int r=0;r<NR;r++) s_acc[wv][r][w] = acc[r];
  __syncthreads();
  {
    int r = tid>>6, k = tid&63;
    float s = s_acc[0][r][k]+s_acc[1][r][k]+s_acc[2][r][k]+s_acc[3][r][k];
    atomicAdd(&out[b*NR*NW + r*NW + k], s);
  }
}

extern "C" void kernel_launch(void* const* d_in, const int* in_sizes, int n_in,
                              void* d_out, int out_size, void* d_ws, size_t ws_size,
                              hipStream_t stream) {
  (void)in_sizes; (void)n_in; (void)out_size; (void)ws_size;
  const float* xi   = (const float*)d_in[0];
  const float* Wm   = (const float*)d_in[1];
  const float* bW   = (const float*)d_in[2];
  const float* mem  = (const float*)d_in[3];
  const float* link = (const float*)d_in[4];
  const float* prec = (const float*)d_in[5];
  const float* rw   = (const float*)d_in[6];
  const float* wwo  = (const float*)d_in[7];
  const float* uv   = (const float*)d_in[8];
  float* out = (float*)d_out;
  float* ws  = (float*)d_ws;
  float* iface = ws;                  // 30208
  float* wwp   = ws + 30208;          // 65536
  float* uu    = ws + 95744;          // 65536
  float* wcd   = ws + 161280;         // 65536
  float* wcn   = ws + 226816;         // 65536
  float* dots  = ws + 292352;         // 327680 = [b][5][1024]
  float* ldiag = ws + 620032;         // 65536
  float* nrwg  = ws + 685568;         // 262144
  float* RFp   = ws + 947712;         // 4*262144 (4 slices, float4 [b][1024])
  float* C2p   = ws + 1996288;        // 4*262144
  float* C3p   = ws + 3044864;        // 4*262144
  k_zero <<<16, 256, 0, stream>>>((float4*)out, 4096);
  k_iface<<<dim3(NB,2), 256, 0, stream>>>(xi, Wm, bW, iface);
  k_wcos <<<dim3(4,NB), 256, 0, stream>>>(iface, mem, rw, wwo, uv, uu, wcd, wcn);
  k_write2<<<NB, 1024, 0, stream>>>(iface, uu, wcd, wcn, wwp);
  // DIAGNOSTIC (round 12): launch k_link8 twice — bit-identical outputs; the delta
  // vs round 11's total measures k_link8's true duration (it never appears in top-5).
  k_link8<<<dim3(4,4,NB), 256, 0, stream>>>(link, rw, wwp, (float4*)RFp, C2p, C3p, ldiag);
  k_link8<<<dim3(4,4,NB), 256, 0, stream>>>(link, rw, wwp, (float4*)RFp, C2p, C3p, ldiag);
  k_rdots<<<dim3(4,NB), 256, 0, stream>>>(iface, mem, wwp, dots);
  k_rmid <<<NB, 1024, 0, stream>>>(iface, prec, rw, wwp, dots, ldiag, (const float4*)RFp, C2p, C3p, nrwg);
  k_readb<<<dim3(4,NB), 256, 0, stream>>>(iface, mem, wwp, nrwg, out);
}

// Round 13
// 222.558 us; speedup vs baseline: 1.0823x; 1.0823x over previous
//
#include <hip/hip_runtime.h>

#define DELTA 1e-6f

// sizes: b=64, m=1024, w=64, r=4, d=512, iface=471
#define NB 64
#define NM 1024
#define NW 64
#define NR 4
#define ND 512
#define NIF 471

typedef unsigned long long ull;

__device__ __forceinline__ float sigmoidf_(float x){ return 1.0f/(1.0f+expf(-x)); }
__device__ __forceinline__ float softplusf_(float x){ return fmaxf(x,0.0f) + log1pf(expf(-fabsf(x))); }

__device__ __forceinline__ float waveSum(float v){
  #pragma unroll
  for(int o=32;o>0;o>>=1) v += __shfl_down(v,o,64);
  return v;
}
__device__ __forceinline__ float waveMax(float v){
  #pragma unroll
  for(int o=32;o>0;o>>=1) v = fmaxf(v, __shfl_down(v,o,64));
  return v;
}
__device__ __forceinline__ ull shflxor64(ull k, int m){
  unsigned lo = (unsigned)(k & 0xffffffffu), hi = (unsigned)(k>>32);
  lo = (unsigned)__shfl_xor((int)lo, m, 64);
  hi = (unsigned)__shfl_xor((int)hi, m, 64);
  return ((ull)hi<<32)|lo;
}

// ---------------- K0: zero the output (k_readb accumulates into it) ----------------
__global__ __launch_bounds__(256) void k_zero(float4* __restrict__ p, int n4){
  int i = blockIdx.x*256 + threadIdx.x;
  if (i < n4) p[i] = make_float4(0.f,0.f,0.f,0.f);
}

// ---------------- K1: iface = xi @ W + bW (128 blocks) ----------------
__global__ __launch_bounds__(256) void k_iface(const float* __restrict__ xi,
                                               const float* __restrict__ Wm,
                                               const float* __restrict__ bW,
                                               float* __restrict__ iface){
  int b = blockIdx.x, half = blockIdx.y;
  __shared__ float xs[ND];
  for(int k=threadIdx.x;k<ND;k+=256) xs[k]=xi[b*ND+k];
  __syncthreads();
  int c = half*236 + threadIdx.x;
  int cend = half ? NIF : 236;
  if (c < cend){
    float acc = bW[c];
    #pragma unroll 4
    for(int k=0;k<ND;k++) acc = fmaf(xs[k], Wm[k*NIF+c], acc);
    iface[b*NIF+c]=acc;
  }
}

// ---------------- K1b: full-GPU pass over mem for write-content dot/nrm + usage ----------------
__global__ __launch_bounds__(256) void k_wcos(
    const float* __restrict__ iface, const float* __restrict__ mem,
    const float* __restrict__ rw_old, const float* __restrict__ ww_old,
    const float* __restrict__ uv,
    float* __restrict__ uu, float* __restrict__ wcd, float* __restrict__ wcn){
  int b = blockIdx.y;
  int j = blockIdx.x*256 + threadIdx.x;
  __shared__ float wkey[NW];
  const float* ifb = iface + b*NIF;
  if (threadIdx.x < NW) wkey[threadIdx.x] = ifb[260+threadIdx.x];
  __syncthreads();
  float fg0=sigmoidf_(ifb[453]), fg1=sigmoidf_(ifb[454]);
  float fg2=sigmoidf_(ifb[455]), fg3=sigmoidf_(ifb[456]);
  float u0  = uv[b*NM+j];
  float wwo = ww_old[b*NM+j];
  float usage = u0 + (1.0f-u0)*wwo;
  float psi = (1.0f - fg0*rw_old[(b*NR+0)*NM+j])
            * (1.0f - fg1*rw_old[(b*NR+1)*NM+j])
            * (1.0f - fg2*rw_old[(b*NR+2)*NM+j])
            * (1.0f - fg3*rw_old[(b*NR+3)*NM+j]);
  usage *= psi;
  uu[b*NM+j] = DELTA + (1.0f-DELTA)*usage;
  float dot=0.0f, nrm=0.0f;
  const float4* mrow4 = (const float4*)(mem + ((size_t)b*NM + j)*NW);
  #pragma unroll 4
  for(int k=0;k<16;k++){
    float4 mv = mrow4[k];
    const float* wk = wkey + k*4;
    dot = fmaf(mv.x,wk[0],dot); dot = fmaf(mv.y,wk[1],dot);
    dot = fmaf(mv.z,wk[2],dot); dot = fmaf(mv.w,wk[3],dot);
    nrm = fmaf(mv.x,mv.x,nrm); nrm = fmaf(mv.y,mv.y,nrm);
    nrm = fmaf(mv.z,mv.z,nrm); nrm = fmaf(mv.w,mv.w,nrm);
  }
  wcd[b*NM+j]=dot; wcn[b*NM+j]=nrm;
}

// ---------------- K2: softmax + bitonic sort + cumprod + new_write_w ----------------
__global__ __launch_bounds__(1024) void k_write2(
    const float* __restrict__ iface, const float* __restrict__ uu,
    const float* __restrict__ wcd, const float* __restrict__ wcn,
    float* __restrict__ wwp){
  int b = blockIdx.x; int tid = threadIdx.x;
  int lane = tid & 63, wv = tid >> 6;
  __shared__ float wkey[NW];
  __shared__ ull skA[NM];
  __shared__ ull skB[NM];
  __shared__ float fb2[NM];
  __shared__ float red[17];
  __shared__ float s_wp[16], s_wp2[16];
  const float* ifb = iface + b*NIF;
  if (tid < NW) wkey[tid] = ifb[260+tid];
  __syncthreads();
  float sw = softplusf_(1.0f + fmaxf(ifb[324],0.0f));
  float ag = sigmoidf_(ifb[457]);
  float wg = sigmoidf_(ifb[458]);
  float kn=0.0f;
  for(int k=0;k<NW;k++){ float t=wkey[k]; kn += t*t; }
  kn = sqrtf(kn);
  float logit = sw * wcd[b*NM+tid] / ((sqrtf(wcn[b*NM+tid])+DELTA)*(kn+DELTA));
  float m1 = waveMax(logit); if(lane==0) red[wv]=m1; __syncthreads();
  if(tid==0){ float mm=red[0]; for(int i=1;i<16;i++) mm=fmaxf(mm,red[i]); red[16]=mm; } __syncthreads();
  float e = expf(logit - red[16]);
  float s1 = waveSum(e); if(lane==0) red[wv]=s1; __syncthreads();
  if(tid==0){ float ss=0; for(int i=0;i<16;i++) ss+=red[i]; red[16]=ss; } __syncthreads();
  float wcw = e/red[16];
  // ---- bitonic sort of (u, idx): strides<64 via shfl, >=64 via ping-pong LDS ----
  float u = uu[b*NM+tid];
  ull k = ((ull)__float_as_uint(u) << 32) | (unsigned)tid;
  bool useA = true;
  for (int k2=2; k2<=NM; k2<<=1){
    for (int jj=k2>>1; jj>0; jj>>=1){
      ull p;
      if (jj >= 64){
        ull* buf = useA ? skA : skB;
        buf[tid] = k;
        __syncthreads();
        p = buf[tid^jj];
        useA = !useA;
      } else {
        p = shflxor64(k, jj);
      }
      bool lower = (tid & jj) == 0;
      bool asc   = (tid & k2) == 0;
      bool takeMin = (lower == asc);
      k = takeMin ? (k<p ? k : p) : (k>p ? k : p);
    }
  }
  float su = __uint_as_float((unsigned)(k>>32));
  int phi  = (int)(k & 0xffffffffu);
  // ---- inclusive cumprod: wave scan + cross-wave prefix ----
  float sc = su;
  #pragma unroll
  for (int off=1; off<64; off<<=1){
    float t = __shfl_up(sc, off, 64);
    if (lane >= off) sc *= t;
  }
  if (lane==63) s_wp[wv] = sc;
  __syncthreads();
  if (tid==0){
    float p=1.0f;
    for (int w=0;w<16;w++){ float t=s_wp[w]; s_wp2[w]=p; p*=t; }
  }
  __syncthreads();
  float P = sc * s_wp2[wv];
  float salloc = (1.0f - su)*P;
  fb2[phi] = salloc;
  __syncthreads();
  float alloc = fb2[tid];
  wwp[b*NM+tid] = wg*(ag*alloc + (1.0f-ag)*wcw);
}

// ---------------- K3: streaming pass over L with T14 async-STAGE split ----------------
// = round-11 k_link8 (measured 82.2us via round-12 double-launch; HBM floor ~45) with the
// stage->barrier serialization removed:
//  * chunk ch+1's 8 rows (+ tables) are loaded into REGISTERS right after staging chunk ch
//    (issue-early / write-late, T14): HBM latency hides under compute(ch).
//  * the 3 per-chunk __syncthreads() are replaced by "s_waitcnt lgkmcnt(0)" + raw s_barrier:
//    LDS-ordered, but prefetch loads stay in flight (HIP __syncthreads would drain vmcnt(0)
//    right after issue, defeating the prefetch — the m97 barrier-drain stall).
//    Compiler-inserted counted vmcnt waits land exactly at next chunk's ds_writes.
// Everything else (swizzle, phase R/C math, partial-slice outputs) is byte-identical to link8.
__global__ __launch_bounds__(256) void k_link9(
    const float* __restrict__ link, const float* __restrict__ rw,
    const float* __restrict__ wwp,
    float4* __restrict__ RFp, float* __restrict__ C2p, float* __restrict__ C3p,
    float* __restrict__ ldiag){
  int cx = blockIdx.x, ry = blockIdx.y, b = blockIdx.z;
  int tid = threadIdx.x, lane = tid&63, wv = tid>>6;
  __shared__ float4 s_L4[32*64];   // 32KB
  __shared__ float4 s_gcol4[256];  // 4KB {g0..g3} per col
  __shared__ float  s_mwc[256];    // 1KB: 1-ww[col]
  __shared__ float4 s_grow4[32];
  __shared__ float  s_wwr[32];
  __shared__ float4 s_rfp4[128];
  const float* Lb = link + ((size_t)b<<20);
  int colbase = cx*256, rowbase = ry*256;
  {
    float g0 = rw[(b*NR+0)*NM + colbase + tid];
    float g1 = rw[(b*NR+1)*NM + colbase + tid];
    float g2 = rw[(b*NR+2)*NM + colbase + tid];
    float g3 = rw[(b*NR+3)*NM + colbase + tid];
    s_gcol4[tid] = make_float4(g0,g1,g2,g3);
    s_mwc[tid] = 1.0f - wwp[b*NM + colbase + tid];
  }
  float c2a[NR][4], c3a[NR][4];
  #pragma unroll
  for(int r=0;r<NR;r++){
    #pragma unroll
    for(int e=0;e<4;e++){ c2a[r][e]=0.0f; c3a[r][e]=0.0f; }
  }
  // prefetch chunk 0 into registers
  float4 pre[8];
  float grow_pre = 0.0f, wwr_pre = 0.0f;
  {
    #pragma unroll
    for (int jq=0;jq<8;jq++){
      int rl = wv + 4*jq;
      pre[jq] = *(const float4*)(Lb + (size_t)(rowbase+rl)*NM + colbase + lane*4);
    }
    if (tid < 128) grow_pre = rw[(b*NR+(tid&3))*NM + rowbase + (tid>>2)];
    if (tid < 32)  wwr_pre  = wwp[b*NM + rowbase + tid];
  }
  for (int ch=0; ch<8; ++ch){
    int rb = rowbase + ch*32;
    // stage prefetched chunk into LDS (prev compute done: barrier B3 of prev iter)
    if (tid < 128) ((float*)s_grow4)[tid] = grow_pre;
    if (tid < 32)  s_wwr[tid] = wwr_pre;
    #pragma unroll
    for (int jq=0;jq<8;jq++){
      int rl = wv + 4*jq;
      s_L4[rl*64 + (lane ^ ((rl>>1)&7))] = pre[jq];
    }
    // issue next chunk's loads — latency hides under compute below (T14)
    if (ch < 7){
      int rbn = rb + 32;
      #pragma unroll
      for (int jq=0;jq<8;jq++){
        int rl = wv + 4*jq;
        pre[jq] = *(const float4*)(Lb + (size_t)(rbn+rl)*NM + colbase + lane*4);
      }
      if (tid < 128) grow_pre = rw[(b*NR+(tid&3))*NM + rbn + (tid>>2)];
      if (tid < 32)  wwr_pre  = wwp[b*NM + rbn + tid];
    }
    asm volatile("s_waitcnt lgkmcnt(0)" ::: "memory");
    __builtin_amdgcn_s_barrier();        // B1: s_L4/tables ready; pre[] stays in flight
    // diag export (cx==ry blocks contain the diagonal of this row range)
    if (cx == ry && tid < 32){
      int coff = ch*32 + tid;
      float4 v = s_L4[tid*64 + ((coff>>2) ^ ((tid>>1)&7))];
      float d = (coff&1) ? ((coff&2)? v.w : v.y) : ((coff&2)? v.z : v.x);
      ldiag[b*NM + rb + tid] = d;
    }
    // ---- phase R: lane owns rows {2i,2i+1}, 16 cols (cg) ----
    {
      int i5 = lane & 15, cg = lane >> 4;
      int rl0 = 2*i5;
      int sz = i5 & 7;               // (rl0>>1)&7, same for both rows
      float wwj0 = s_wwr[rl0], wwj1 = s_wwr[rl0+1];
      float rf0[4] = {0,0,0,0}, rf1[4] = {0,0,0,0};
      #pragma unroll
      for (int q=0;q<4;q++){
        int cq = wv*16 + cg*4 + q;
        float4 mw  = ((const float4*)s_mwc)[cq];
        float4 lv0 = s_L4[rl0*64 + (cq ^ sz)];
        float4 lv1 = s_L4[(rl0+1)*64 + (cq ^ sz)];
        float le0[4]={lv0.x,lv0.y,lv0.z,lv0.w};
        float le1[4]={lv1.x,lv1.y,lv1.z,lv1.w};
        float mv[4]={mw.x,mw.y,mw.z,mw.w};
        #pragma unroll
        for (int e=0;e<4;e++){
          float4 gv = s_gcol4[cq*4+e];
          float lt0 = le0[e]*(mv[e]-wwj0);
          float lt1 = le1[e]*(mv[e]-wwj1);
          rf0[0]=fmaf(lt0,gv.x,rf0[0]); rf0[1]=fmaf(lt0,gv.y,rf0[1]);
          rf0[2]=fmaf(lt0,gv.z,rf0[2]); rf0[3]=fmaf(lt0,gv.w,rf0[3]);
          rf1[0]=fmaf(lt1,gv.x,rf1[0]); rf1[1]=fmaf(lt1,gv.y,rf1[1]);
          rf1[2]=fmaf(lt1,gv.z,rf1[2]); rf1[3]=fmaf(lt1,gv.w,rf1[3]);
        }
      }
      // sum the 4 col-groups (lanes i, i+16, i+32, i+48)
      #pragma unroll
      for (int r=0;r<NR;r++){
        rf0[r] += __shfl_xor(rf0[r], 16, 64);
        rf0[r] += __shfl_xor(rf0[r], 32, 64);
        rf1[r] += __shfl_xor(rf1[r], 16, 64);
        rf1[r] += __shfl_xor(rf1[r], 32, 64);
      }
      if (cg == 0){
        s_rfp4[wv*32 + rl0]     = make_float4(rf0[0],rf0[1],rf0[2],rf0[3]);
        s_rfp4[wv*32 + rl0 + 1] = make_float4(rf1[0],rf1[1],rf1[2],rf1[3]);
      }
    }
    // ---- phase C: wave covers 8 rows, lane owns 4 cols ----
    #pragma unroll 2
    for (int ri=0; ri<8; ri++){
      int row = wv*8 + ri;
      float4 lv = s_L4[row*64 + (lane ^ ((row>>1)&7))];
      float4 gg = s_grow4[row];
      float wwr = s_wwr[row];
      float le[4] = {lv.x,lv.y,lv.z,lv.w};
      float ggv[4] = {gg.x,gg.y,gg.z,gg.w};
      float ggw[4];
      #pragma unroll
      for (int r=0;r<NR;r++) ggw[r] = ggv[r]*wwr;
      #pragma unroll
      for (int e=0;e<4;e++){
        #pragma unroll
        for (int r=0;r<NR;r++){
          c2a[r][e] = fmaf(le[e], ggv[r], c2a[r][e]);
          c3a[r][e] = fmaf(le[e], ggw[r], c3a[r][e]);
        }
      }
    }
    asm volatile("s_waitcnt lgkmcnt(0)" ::: "memory");
    __builtin_amdgcn_s_barrier();        // B2: s_rfp4 complete, s_L4 free
    if (tid < 128){
      int row = tid>>2, r = tid&3;
      float s = ((const float*)&s_rfp4[0*32+row])[r] + ((const float*)&s_rfp4[1*32+row])[r]
              + ((const float*)&s_rfp4[2*32+row])[r] + ((const float*)&s_rfp4[3*32+row])[r];
      ((float*)RFp)[((size_t)cx<<18) + (b*NM + rb + row)*4 + r] = s;
    }
    asm volatile("s_waitcnt lgkmcnt(0)" ::: "memory");
    __builtin_amdgcn_s_barrier();        // B3: s_rfp4 free for next chunk
  }
  // ---- c2/c3 cross-wave combine (reuse s_L4), plain float4 stores to own slice ----
  float4* s_comb = s_L4;
  #pragma unroll
  for (int r=0;r<NR;r++){
    s_comb[tid*8 + r]     = make_float4(c2a[r][0],c2a[r][1],c2a[r][2],c2a[r][3]);
    s_comb[tid*8 + 4 + r] = make_float4(c3a[r][0],c3a[r][1],c3a[r][2],c3a[r][3]);
  }
  asm volatile("s_waitcnt lgkmcnt(0)" ::: "memory");
  __builtin_amdgcn_s_barrier();
  for (int t=tid; t<512; t+=256){
    int lc = t>>3, q = t&7;
    float4 a = s_comb[(0*64+lc)*8+q];
    float4 bb= s_comb[(1*64+lc)*8+q];
    float4 c = s_comb[(2*64+lc)*8+q];
    float4 d = s_comb[(3*64+lc)*8+q];
    float4 s = make_float4(a.x+bb.x+c.x+d.x, a.y+bb.y+c.y+d.y, a.z+bb.z+c.z+d.z, a.w+bb.w+c.w+d.w);
    float* dst = (q<4) ? &C2p[((size_t)ry<<18) + (b*NR+q)*NM + colbase + lc*4]
                       : &C3p[((size_t)ry<<18) + (b*NR+(q-4))*NM + colbase + lc*4];
    *(float4*)dst = s;
  }
}

// ---------------- K4a: full-GPU pass over mem for read-content dots/nrm ----------------
__global__ __launch_bounds__(256) void k_rdots(
    const float* __restrict__ iface, const float* __restrict__ mem,
    const float* __restrict__ wwp, float* __restrict__ dots){
  int b = blockIdx.y;
  int j = blockIdx.x*256 + threadIdx.x;
  __shared__ float keys[NR][NW];
  __shared__ float er[NW], wvec[NW];
  const float* ifb = iface + b*NIF;
  { int r=threadIdx.x>>6, kk=threadIdx.x&63; keys[r][kk] = ifb[r*NW+kk]; }
  if (threadIdx.x < 64) er[threadIdx.x] = sigmoidf_(ifb[325+threadIdx.x]);
  else if (threadIdx.x < 128) wvec[threadIdx.x-64] = ifb[389+threadIdx.x-64];
  __syncthreads();
  float wwj = wwp[b*NM+j];
  const float* mrow = mem + ((size_t)b*NM+j)*NW;
  float dt[NR]={0,0,0,0}; float nrm=0.0f;
  for(int k=0;k<NW;k++){
    float nmv = fmaf(mrow[k], (1.0f - wwj*er[k]), wwj*wvec[k]);
    nrm = fmaf(nmv,nmv,nrm);
    #pragma unroll
    for(int r=0;r<NR;r++) dt[r] = fmaf(nmv, keys[r][k], dt[r]);
  }
  #pragma unroll
  for(int r=0;r<NR;r++) dots[(b*5+r)*NM + j] = dt[r];
  dots[(b*5+4)*NM + j] = nrm;
}

// ---------------- K4b: Pr/Kr + read softmax + fwd/bwd finalize -> nrw (sums partial slices inline) ----------------
__global__ __launch_bounds__(1024) void k_rmid(
    const float* __restrict__ iface, const float* __restrict__ prec,
    const float* __restrict__ rw_old, const float* __restrict__ wwp,
    const float* __restrict__ dots, const float* __restrict__ ldiag,
    const float4* __restrict__ RFp4, const float* __restrict__ C2p, const float* __restrict__ C3p,
    float* __restrict__ nrwg){
  int b = blockIdx.x; int tid = threadIdx.x; int lane=tid&63, wv=tid>>6;
  __shared__ float s_pk[16][8];
  __shared__ float scal[16];   // [0..3]=Pr, [4..7]=Kr, [8..11]=keynorm, [12..15]=strength
  __shared__ float smax[NR], ssum[NR];
  __shared__ float rm[NR][3];
  const float* ifb = iface + b*NIF;
  if (tid == 0){
    for(int mo=0;mo<3;mo++){
      float x0=ifb[458+0*3+mo], x1=ifb[458+1*3+mo], x2=ifb[458+2*3+mo], x3=ifb[458+3*3+mo];
      float mx = fmaxf(fmaxf(x0,x1),fmaxf(x2,x3));
      float e0=expf(x0-mx),e1=expf(x1-mx),e2=expf(x2-mx),e3=expf(x3-mx);
      float s=e0+e1+e2+e3;
      rm[0][mo]=e0/s; rm[1][mo]=e1/s; rm[2][mo]=e2/s; rm[3][mo]=e3/s;
    }
  }
  if (tid >= 320 && tid < 324){
    int r = tid-320;
    float knv=0;
    for(int k=0;k<NW;k++){ float t=ifb[r*NW+k]; knv += t*t; }
    scal[8+r]  = sqrtf(knv);
    scal[12+r] = softplusf_(1.0f + fmaxf(ifb[256+r],0.0f));
  }
  __syncthreads();
  int j = tid;
  float pj  = prec[b*NM+j];
  float wwj = wwp[b*NM+j];
  float rwv[NR];
  #pragma unroll
  for(int r=0;r<NR;r++) rwv[r]=rw_old[(b*NR+r)*NM+j];
  {
    float v8[8];
    #pragma unroll
    for(int r=0;r<NR;r++){ v8[r] = pj*rwv[r]; v8[4+r] = wwj*rwv[r]; }
    #pragma unroll
    for(int q=0;q<8;q++){
      float s = waveSum(v8[q]);
      if(lane==0) s_pk[wv][q]=s;
    }
    __syncthreads();
    if (tid < 8){
      float ss=0;
      for(int w=0;w<16;w++) ss += s_pk[w][tid];
      scal[tid]=ss;
    }
    __syncthreads();
  }
  float dt[NR];
  #pragma unroll
  for(int r=0;r<NR;r++) dt[r] = dots[(b*5+r)*NM + j];
  float nrm = dots[(b*5+4)*NM + j];
  float inv = 1.0f/(sqrtf(nrm)+DELTA);
  float logit[NR], ce[NR], cw[NR];
  #pragma unroll
  for(int r=0;r<NR;r++) logit[r] = scal[12+r]*dt[r]*inv/(scal[8+r]+DELTA);
  #pragma unroll
  for(int r=0;r<NR;r++){
    float m1 = waveMax(logit[r]);
    if(lane==0) s_pk[wv][r]=m1;
  }
  __syncthreads();
  if (tid < NR){
    float mm=s_pk[0][tid];
    for(int w=1;w<16;w++) mm=fmaxf(mm,s_pk[w][tid]);
    smax[tid]=mm;
  }
  __syncthreads();
  #pragma unroll
  for(int r=0;r<NR;r++){
    ce[r] = expf(logit[r]-smax[r]);
    float s1 = waveSum(ce[r]);
    if(lane==0) s_pk[wv][r]=s1;
  }
  __syncthreads();
  if (tid < NR){
    float ss=0;
    for(int w=0;w<16;w++) ss += s_pk[w][tid];
    ssum[tid]=ss;
  }
  __syncthreads();
  #pragma unroll
  for(int r=0;r<NR;r++) cw[r] = ce[r]/ssum[r];
  float Ljj = ldiag[b*NM+j];
  // inline combine of the 4 partial slices
  float4 Fa = RFp4[(0<<16) + b*NM + j];
  float4 Fb = RFp4[(1<<16) + b*NM + j];
  float4 Fc = RFp4[(2<<16) + b*NM + j];
  float4 Fd = RFp4[(3<<16) + b*NM + j];
  float Fr[4] = {Fa.x+Fb.x+Fc.x+Fd.x, Fa.y+Fb.y+Fc.y+Fd.y,
                 Fa.z+Fb.z+Fc.z+Fd.z, Fa.w+Fb.w+Fc.w+Fd.w};
  #pragma unroll
  for(int r=0;r<NR;r++){
    int idx = (b*NR+r)*NM + j;
    float cc2 = C2p[idx] + C2p[262144+idx] + C2p[524288+idx] + C2p[786432+idx];
    float cc3 = C3p[idx] + C3p[262144+idx] + C3p[524288+idx] + C3p[786432+idx];
    float F   = Fr[r];
    float grj = rwv[r];
    float fwd = F - Ljj*grj*(1.0f-2.0f*wwj) + wwj*(scal[r] - pj*grj);
    float bwd = (cc2 - cc3) - Ljj*grj*(1.0f-wwj) - wwj*(cc2 - Ljj*grj) + pj*(scal[4+r] - wwj*grj);
    nrwg[(b*NR+r)*NM+j] = rm[r][0]*bwd + rm[r][1]*fwd + rm[r][2]*cw[r];
  }
}

// ---------------- K4c: read_vectors = nrw @ new_memory, 256-block partial matmul ----------------
__global__ __launch_bounds__(256) void k_readb(
    const float* __restrict__ iface, const float* __restrict__ mem,
    const float* __restrict__ wwp, const float* __restrict__ nrwg,
    float* __restrict__ out){
  int jt = blockIdx.x, b = blockIdx.y;
  int tid = threadIdx.x, lane = tid&63, wv = tid>>6;
  __shared__ float s_nrw[NR][256];
  __shared__ float s_ww[256];
  __shared__ float s_er[NW], s_wv[NW];
  __shared__ float s_acc[4][NR][NW];
  const float* ifb = iface + b*NIF;
  int j0 = jt*256;
  #pragma unroll
  for(int r=0;r<NR;r++) s_nrw[r][tid] = nrwg[(b*NR+r)*NM + j0+tid];
  s_ww[tid] = wwp[b*NM + j0+tid];
  if (tid < 64) s_er[tid] = sigmoidf_(ifb[325+tid]);
  else if (tid < 128) s_wv[tid-64] = ifb[389+tid-64];
  __syncthreads();
  int w = lane;
  float erw = s_er[w], wvw = s_wv[w];
  float acc[NR]={0,0,0,0};
  for(int jj=0;jj<64;jj++){
    int jl = wv*64+jj;
    float wwr = s_ww[jl];
    float nmv = fmaf(mem[((size_t)b*NM + j0+jl)*NW + w], (1.0f - wwr*erw), wwr*wvw);
    #pragma unroll
    for(int r=0;r<NR;r++) acc[r] = fmaf(s_nrw[r][jl], nmv, acc[r]);
  }
  #pragma unroll
  for(int r=0;r<NR;r++) s_acc[wv][r][w] = acc[r];
  __syncthreads();
  {
    int r = tid>>6, k = tid&63;
    float s = s_acc[0][r][k]+s_acc[1][r][k]+s_acc[2][r][k]+s_acc[3][r][k];
    atomicAdd(&out[b*NR*NW + r*NW + k], s);
  }
}

extern "C" void kernel_launch(void* const* d_in, const int* in_sizes, int n_in,
                              void* d_out, int out_size, void* d_ws, size_t ws_size,
                              hipStream_t stream) {
  (void)in_sizes; (void)n_in; (void)out_size; (void)ws_size;
  const float* xi   = (const float*)d_in[0];
  const float* Wm   = (const float*)d_in[1];
  const float* bW   = (const float*)d_in[2];
  const float* mem  = (const float*)d_in[3];
  const float* link = (const float*)d_in[4];
  const float* prec = (const float*)d_in[5];
  const float* rw   = (const float*)d_in[6];
  const float* wwo  = (const float*)d_in[7];
  const float* uv   = (const float*)d_in[8];
  float* out = (float*)d_out;
  float* ws  = (float*)d_ws;
  float* iface = ws;                  // 30208
  float* wwp   = ws + 30208;          // 65536
  float* uu    = ws + 95744;          // 65536
  float* wcd   = ws + 161280;         // 65536
  float* wcn   = ws + 226816;         // 65536
  float* dots  = ws + 292352;         // 327680 = [b][5][1024]
  float* ldiag = ws + 620032;         // 65536
  float* nrwg  = ws + 685568;         // 262144
  float* RFp   = ws + 947712;         // 4*262144 (4 slices, float4 [b][1024])
  float* C2p   = ws + 1996288;        // 4*262144
  float* C3p   = ws + 3044864;        // 4*262144
  k_zero <<<16, 256, 0, stream>>>((float4*)out, 4096);
  k_iface<<<dim3(NB,2), 256, 0, stream>>>(xi, Wm, bW, iface);
  k_wcos <<<dim3(4,NB), 256, 0, stream>>>(iface, mem, rw, wwo, uv, uu, wcd, wcn);
  k_write2<<<NB, 1024, 0, stream>>>(iface, uu, wcd, wcn, wwp);
  k_link9<<<dim3(4,4,NB), 256, 0, stream>>>(link, rw, wwp, (float4*)RFp, C2p, C3p, ldiag);
  k_rdots<<<dim3(4,NB), 256, 0, stream>>>(iface, mem, wwp, dots);
  k_rmid <<<NB, 1024, 0, stream>>>(iface, prec, rw, wwp, dots, ldiag, (const float4*)RFp, C2p, C3p, nrwg);
  k_readb<<<dim3(4,NB), 256, 0, stream>>>(iface, mem, wwp, nrwg, out);
}

// Round 14
// 161.657 us; speedup vs baseline: 1.4900x; 1.3767x over previous
//
#include <hip/hip_runtime.h>

#define DELTA 1e-6f

// sizes: b=64, m=1024, w=64, r=4, d=512, iface=471
#define NB 64
#define NM 1024
#define NW 64
#define NR 4
#define ND 512
#define NIF 471

typedef unsigned long long ull;

__device__ __forceinline__ float sigmoidf_(float x){ return 1.0f/(1.0f+expf(-x)); }
__device__ __forceinline__ float softplusf_(float x){ return fmaxf(x,0.0f) + log1pf(expf(-fabsf(x))); }

__device__ __forceinline__ float waveSum(float v){
  #pragma unroll
  for(int o=32;o>0;o>>=1) v += __shfl_down(v,o,64);
  return v;
}
__device__ __forceinline__ float waveMax(float v){
  #pragma unroll
  for(int o=32;o>0;o>>=1) v = fmaxf(v, __shfl_down(v,o,64));
  return v;
}
__device__ __forceinline__ ull shflxor64(ull k, int m){
  unsigned lo = (unsigned)(k & 0xffffffffu), hi = (unsigned)(k>>32);
  lo = (unsigned)__shfl_xor((int)lo, m, 64);
  hi = (unsigned)__shfl_xor((int)hi, m, 64);
  return ((ull)hi<<32)|lo;
}

// ---------------- K1: iface = xi @ W + bW (128 blocks) ----------------
__global__ __launch_bounds__(256) void k_iface(const float* __restrict__ xi,
                                               const float* __restrict__ Wm,
                                               const float* __restrict__ bW,
                                               float* __restrict__ iface){
  int b = blockIdx.x, half = blockIdx.y;
  __shared__ float xs[ND];
  for(int k=threadIdx.x;k<ND;k+=256) xs[k]=xi[b*ND+k];
  __syncthreads();
  int c = half*236 + threadIdx.x;
  int cend = half ? NIF : 236;
  if (c < cend){
    float acc = bW[c];
    #pragma unroll 4
    for(int k=0;k<ND;k++) acc = fmaf(xs[k], Wm[k*NIF+c], acc);
    iface[b*NIF+c]=acc;
  }
}

// ---------------- K1b: full-GPU pass over mem for write-content dot/nrm + usage ----------------
__global__ __launch_bounds__(256) void k_wcos(
    const float* __restrict__ iface, const float* __restrict__ mem,
    const float* __restrict__ rw_old, const float* __restrict__ ww_old,
    const float* __restrict__ uv,
    float* __restrict__ uu, float* __restrict__ wcd, float* __restrict__ wcn){
  int b = blockIdx.y;
  int j = blockIdx.x*256 + threadIdx.x;
  __shared__ float wkey[NW];
  const float* ifb = iface + b*NIF;
  if (threadIdx.x < NW) wkey[threadIdx.x] = ifb[260+threadIdx.x];
  __syncthreads();
  float fg0=sigmoidf_(ifb[453]), fg1=sigmoidf_(ifb[454]);
  float fg2=sigmoidf_(ifb[455]), fg3=sigmoidf_(ifb[456]);
  float u0  = uv[b*NM+j];
  float wwo = ww_old[b*NM+j];
  float usage = u0 + (1.0f-u0)*wwo;
  float psi = (1.0f - fg0*rw_old[(b*NR+0)*NM+j])
            * (1.0f - fg1*rw_old[(b*NR+1)*NM+j])
            * (1.0f - fg2*rw_old[(b*NR+2)*NM+j])
            * (1.0f - fg3*rw_old[(b*NR+3)*NM+j]);
  usage *= psi;
  uu[b*NM+j] = DELTA + (1.0f-DELTA)*usage;
  float dot=0.0f, nrm=0.0f;
  const float4* mrow4 = (const float4*)(mem + ((size_t)b*NM + j)*NW);
  #pragma unroll 4
  for(int k=0;k<16;k++){
    float4 mv = mrow4[k];
    const float* wk = wkey + k*4;
    dot = fmaf(mv.x,wk[0],dot); dot = fmaf(mv.y,wk[1],dot);
    dot = fmaf(mv.z,wk[2],dot); dot = fmaf(mv.w,wk[3],dot);
    nrm = fmaf(mv.x,mv.x,nrm); nrm = fmaf(mv.y,mv.y,nrm);
    nrm = fmaf(mv.z,mv.z,nrm); nrm = fmaf(mv.w,mv.w,nrm);
  }
  wcd[b*NM+j]=dot; wcn[b*NM+j]=nrm;
}

// ---------------- K2: softmax + bitonic sort + cumprod + new_write_w ----------------
__global__ __launch_bounds__(1024) void k_write2(
    const float* __restrict__ iface, const float* __restrict__ uu,
    const float* __restrict__ wcd, const float* __restrict__ wcn,
    float* __restrict__ wwp){
  int b = blockIdx.x; int tid = threadIdx.x;
  int lane = tid & 63, wv = tid >> 6;
  __shared__ float wkey[NW];
  __shared__ ull skA[NM];
  __shared__ ull skB[NM];
  __shared__ float fb2[NM];
  __shared__ float red[17];
  __shared__ float s_wp[16], s_wp2[16];
  const float* ifb = iface + b*NIF;
  if (tid < NW) wkey[tid] = ifb[260+tid];
  __syncthreads();
  float sw = softplusf_(1.0f + fmaxf(ifb[324],0.0f));
  float ag = sigmoidf_(ifb[457]);
  float wg = sigmoidf_(ifb[458]);
  float kn=0.0f;
  for(int k=0;k<NW;k++){ float t=wkey[k]; kn += t*t; }
  kn = sqrtf(kn);
  float logit = sw * wcd[b*NM+tid] / ((sqrtf(wcn[b*NM+tid])+DELTA)*(kn+DELTA));
  float m1 = waveMax(logit); if(lane==0) red[wv]=m1; __syncthreads();
  if(tid==0){ float mm=red[0]; for(int i=1;i<16;i++) mm=fmaxf(mm,red[i]); red[16]=mm; } __syncthreads();
  float e = expf(logit - red[16]);
  float s1 = waveSum(e); if(lane==0) red[wv]=s1; __syncthreads();
  if(tid==0){ float ss=0; for(int i=0;i<16;i++) ss+=red[i]; red[16]=ss; } __syncthreads();
  float wcw = e/red[16];
  float u = uu[b*NM+tid];
  ull k = ((ull)__float_as_uint(u) << 32) | (unsigned)tid;
  bool useA = true;
  for (int k2=2; k2<=NM; k2<<=1){
    for (int jj=k2>>1; jj>0; jj>>=1){
      ull p;
      if (jj >= 64){
        ull* buf = useA ? skA : skB;
        buf[tid] = k;
        __syncthreads();
        p = buf[tid^jj];
        useA = !useA;
      } else {
        p = shflxor64(k, jj);
      }
      bool lower = (tid & jj) == 0;
      bool asc   = (tid & k2) == 0;
      bool takeMin = (lower == asc);
      k = takeMin ? (k<p ? k : p) : (k>p ? k : p);
    }
  }
  float su = __uint_as_float((unsigned)(k>>32));
  int phi  = (int)(k & 0xffffffffu);
  float sc = su;
  #pragma unroll
  for (int off=1; off<64; off<<=1){
    float t = __shfl_up(sc, off, 64);
    if (lane >= off) sc *= t;
  }
  if (lane==63) s_wp[wv] = sc;
  __syncthreads();
  if (tid==0){
    float p=1.0f;
    for (int w=0;w<16;w++){ float t=s_wp[w]; s_wp2[w]=p; p*=t; }
  }
  __syncthreads();
  float P = sc * s_wp2[wv];
  float salloc = (1.0f - su)*P;
  fb2[phi] = salloc;
  __syncthreads();
  float alloc = fb2[tid];
  wwp[b*NM+tid] = wg*(ag*alloc + (1.0f-ag)*wcw);
}

// ---------------- K3: fused link pass + rdots + out-zero ----------------
// grid (4, 5, 64): ry<4 -> link tile (cx,ry,b); ry==4 -> rdots for (jt=cx, b) (+ out zeroing).
// Link path vs round-11 link8: chunk 32->16 rows, row tables for the whole 256-row strip
// loaded ONCE upfront, LDS 39.6->~28KB -> 5 blocks/CU (grid = exactly 5/CU incl. rdots
// blocks). Lever is TLP (m114: implicit wave-overlap hides the stage stall) — rounds 10/13
// showed per-row butterflies and cross-barrier reg-prefetch both lose; plain __syncthreads,
// no prefetch registers, live set ~80 VGPR (spill-proof under the 5-wave/SIMD ~102 cap).
__global__ __launch_bounds__(256) void k_linkr(
    const float* __restrict__ link, const float* __restrict__ rw,
    const float* __restrict__ wwp,
    float* __restrict__ RFp, float* __restrict__ C2p, float* __restrict__ C3p,
    float* __restrict__ ldiag,
    const float* __restrict__ iface, const float* __restrict__ mem,
    float* __restrict__ dots, float4* __restrict__ out4){
  __shared__ float4 s_L4[16*64];   // 16KB (reused as combine buffer at the end)
  __shared__ float4 s_gcol4[256];  // 4KB {g0..g3} per col
  __shared__ float  s_mwc[256];    // 1KB 1-ww[col]
  __shared__ float4 s_grow4[256];  // 4KB {g0..g3} per row (whole strip)
  __shared__ float  s_wwr[256];    // 1KB ww[row] (whole strip)
  __shared__ float4 s_rfp4[4][16]; // 1KB phase-R partials
  __shared__ float  s_keys[NR][NW];
  __shared__ float  s_er[NW], s_wvec[NW];
  int tid = threadIdx.x, lane = tid&63, wv = tid>>6;
  int b = blockIdx.z;

  if (blockIdx.y == 4){
    // ======== rdots path (jt = blockIdx.x) + out zeroing ========
    int jt = blockIdx.x;
    if (jt == 0 && b < 16) out4[b*256 + tid] = make_float4(0.f,0.f,0.f,0.f);
    const float* ifb = iface + b*NIF;
    { int r=tid>>6, kk=tid&63; s_keys[r][kk] = ifb[r*NW+kk]; }
    if (tid < 64) s_er[tid] = sigmoidf_(ifb[325+tid]);
    else if (tid < 128) s_wvec[tid-64] = ifb[389+tid-64];
    __syncthreads();
    int j = jt*256 + tid;
    float wwj = wwp[b*NM+j];
    const float* mrow = mem + ((size_t)b*NM+j)*NW;
    float dt[NR]={0,0,0,0}; float nrm=0.0f;
    for(int k=0;k<NW;k++){
      float nmv = fmaf(mrow[k], (1.0f - wwj*s_er[k]), wwj*s_wvec[k]);
      nrm = fmaf(nmv,nmv,nrm);
      #pragma unroll
      for(int r=0;r<NR;r++) dt[r] = fmaf(nmv, s_keys[r][k], dt[r]);
    }
    #pragma unroll
    for(int r=0;r<NR;r++) dots[(b*5+r)*NM + j] = dt[r];
    dots[(b*5+4)*NM + j] = nrm;
    return;
  }

  // ======== link path ========
  int cx = blockIdx.x, ry = blockIdx.y;
  const float* Lb = link + ((size_t)b<<20);
  int colbase = cx*256, rowbase = ry*256;
  {
    float g0 = rw[(b*NR+0)*NM + colbase + tid];
    float g1 = rw[(b*NR+1)*NM + colbase + tid];
    float g2 = rw[(b*NR+2)*NM + colbase + tid];
    float g3 = rw[(b*NR+3)*NM + colbase + tid];
    s_gcol4[tid] = make_float4(g0,g1,g2,g3);
    s_mwc[tid] = 1.0f - wwp[b*NM + colbase + tid];
    for (int t=tid; t<1024; t+=256)
      ((float*)s_grow4)[t] = rw[(b*NR+(t&3))*NM + rowbase + (t>>2)];
    s_wwr[tid] = wwp[b*NM + rowbase + tid];
  }
  float c2a[NR][4], c3a[NR][4];
  #pragma unroll
  for(int r=0;r<NR;r++){
    #pragma unroll
    for(int e=0;e<4;e++){ c2a[r][e]=0.0f; c3a[r][e]=0.0f; }
  }
  const bool isdiag = (cx==ry);
  for (int ch=0; ch<16; ++ch){
    int rb = rowbase + ch*16;
    // stage 16 rows (each wave 4)
    #pragma unroll
    for (int jq=0;jq<4;jq++){
      int rl = wv + 4*jq;
      int sz = (rl>>1)&7;
      float4 lv = *(const float4*)(Lb + (size_t)(rb+rl)*NM + colbase + lane*4);
      s_L4[rl*64 + (lane ^ sz)] = lv;
    }
    __syncthreads();   // B1: chunk staged
    if (isdiag && tid < 16){
      int lr = tid, coff = ch*16 + lr, cq = coff>>2;
      float4 v = s_L4[lr*64 + (cq ^ ((lr>>1)&7))];
      float d = (coff&1) ? ((coff&2)? v.w : v.y) : ((coff&2)? v.z : v.x);
      ldiag[b*NM + rb + lr] = d;
    }
    // ---- phase R: lane owns row i5, 16 cols (cg) ----
    {
      int i5 = lane & 15, cg = lane >> 4;
      int sz = (i5>>1)&7;
      float wwj = s_wwr[ch*16 + i5];
      float rf[4] = {0,0,0,0};
      #pragma unroll
      for (int q=0;q<4;q++){
        int cq = wv*16 + cg*4 + q;
        float4 mw = ((const float4*)s_mwc)[cq];
        float4 lv = s_L4[i5*64 + (cq ^ sz)];
        float le[4]={lv.x,lv.y,lv.z,lv.w};
        float mv[4]={mw.x,mw.y,mw.z,mw.w};
        #pragma unroll
        for (int e=0;e<4;e++){
          float4 gv = s_gcol4[cq*4+e];
          float lt = le[e]*(mv[e]-wwj);
          rf[0]=fmaf(lt,gv.x,rf[0]); rf[1]=fmaf(lt,gv.y,rf[1]);
          rf[2]=fmaf(lt,gv.z,rf[2]); rf[3]=fmaf(lt,gv.w,rf[3]);
        }
      }
      #pragma unroll
      for (int r=0;r<NR;r++){
        rf[r] += __shfl_xor(rf[r], 16, 64);
        rf[r] += __shfl_xor(rf[r], 32, 64);
      }
      if (cg == 0) s_rfp4[wv][i5] = make_float4(rf[0],rf[1],rf[2],rf[3]);
    }
    // ---- phase C: wave covers 4 rows, lane owns 4 cols ----
    #pragma unroll
    for (int ri=0; ri<4; ri++){
      int row = wv*4 + ri;
      float4 lv = s_L4[row*64 + (lane ^ ((row>>1)&7))];
      float4 gg = s_grow4[ch*16+row];
      float wwr = s_wwr[ch*16+row];
      float le[4] = {lv.x,lv.y,lv.z,lv.w};
      float ggv[4] = {gg.x,gg.y,gg.z,gg.w};
      float ggw[4];
      #pragma unroll
      for (int r=0;r<NR;r++) ggw[r] = ggv[r]*wwr;
      #pragma unroll
      for (int e=0;e<4;e++){
        #pragma unroll
        for (int r=0;r<NR;r++){
          c2a[r][e] = fmaf(le[e], ggv[r], c2a[r][e]);
          c3a[r][e] = fmaf(le[e], ggw[r], c3a[r][e]);
        }
      }
    }
    __syncthreads();   // B2: s_rfp4 ready, all s_L4 reads done
    if (tid < 64){
      int row = tid>>2, r = tid&3;
      float s = ((const float*)&s_rfp4[0][row])[r] + ((const float*)&s_rfp4[1][row])[r]
              + ((const float*)&s_rfp4[2][row])[r] + ((const float*)&s_rfp4[3][row])[r];
      RFp[((size_t)cx<<18) + (size_t)(b*NM + rb + row)*4 + r] = s;
    }
  }
  // ---- c2/c3 cross-wave combine in two 16KB passes (reuse s_L4) ----
  __syncthreads();
  float4* s_comb = s_L4;
  #pragma unroll
  for (int r=0;r<NR;r++) s_comb[tid*4 + r] = make_float4(c2a[r][0],c2a[r][1],c2a[r][2],c2a[r][3]);
  __syncthreads();
  {
    int lc = tid>>2, r = tid&3;
    float4 a = s_comb[(0*64+lc)*4+r];
    float4 bb= s_comb[(1*64+lc)*4+r];
    float4 c = s_comb[(2*64+lc)*4+r];
    float4 d = s_comb[(3*64+lc)*4+r];
    float4 s = make_float4(a.x+bb.x+c.x+d.x, a.y+bb.y+c.y+d.y, a.z+bb.z+c.z+d.z, a.w+bb.w+c.w+d.w);
    *(float4*)&C2p[((size_t)blockIdx.y<<18) + (b*NR+r)*NM + colbase + lc*4] = s;
  }
  __syncthreads();
  #pragma unroll
  for (int r=0;r<NR;r++) s_comb[tid*4 + r] = make_float4(c3a[r][0],c3a[r][1],c3a[r][2],c3a[r][3]);
  __syncthreads();
  {
    int lc = tid>>2, r = tid&3;
    float4 a = s_comb[(0*64+lc)*4+r];
    float4 bb= s_comb[(1*64+lc)*4+r];
    float4 c = s_comb[(2*64+lc)*4+r];
    float4 d = s_comb[(3*64+lc)*4+r];
    float4 s = make_float4(a.x+bb.x+c.x+d.x, a.y+bb.y+c.y+d.y, a.z+bb.z+c.z+d.z, a.w+bb.w+c.w+d.w);
    *(float4*)&C3p[((size_t)blockIdx.y<<18) + (b*NR+r)*NM + colbase + lc*4] = s;
  }
}

// ---------------- K4b: Pr/Kr + read softmax + fwd/bwd finalize -> nrw (sums partial slices inline) ----------------
__global__ __launch_bounds__(1024) void k_rmid(
    const float* __restrict__ iface, const float* __restrict__ prec,
    const float* __restrict__ rw_old, const float* __restrict__ wwp,
    const float* __restrict__ dots, const float* __restrict__ ldiag,
    const float4* __restrict__ RFp4, const float* __restrict__ C2p, const float* __restrict__ C3p,
    float* __restrict__ nrwg){
  int b = blockIdx.x; int tid = threadIdx.x; int lane=tid&63, wv=tid>>6;
  __shared__ float s_pk[16][8];
  __shared__ float scal[16];   // [0..3]=Pr, [4..7]=Kr, [8..11]=keynorm, [12..15]=strength
  __shared__ float smax[NR], ssum[NR];
  __shared__ float rm[NR][3];
  const float* ifb = iface + b*NIF;
  if (tid == 0){
    for(int mo=0;mo<3;mo++){
      float x0=ifb[458+0*3+mo], x1=ifb[458+1*3+mo], x2=ifb[458+2*3+mo], x3=ifb[458+3*3+mo];
      float mx = fmaxf(fmaxf(x0,x1),fmaxf(x2,x3));
      float e0=expf(x0-mx),e1=expf(x1-mx),e2=expf(x2-mx),e3=expf(x3-mx);
      float s=e0+e1+e2+e3;
      rm[0][mo]=e0/s; rm[1][mo]=e1/s; rm[2][mo]=e2/s; rm[3][mo]=e3/s;
    }
  }
  if (tid >= 320 && tid < 324){
    int r = tid-320;
    float knv=0;
    for(int k=0;k<NW;k++){ float t=ifb[r*NW+k]; knv += t*t; }
    scal[8+r]  = sqrtf(knv);
    scal[12+r] = softplusf_(1.0f + fmaxf(ifb[256+r],0.0f));
  }
  __syncthreads();
  int j = tid;
  float pj  = prec[b*NM+j];
  float wwj = wwp[b*NM+j];
  float rwv[NR];
  #pragma unroll
  for(int r=0;r<NR;r++) rwv[r]=rw_old[(b*NR+r)*NM+j];
  {
    float v8[8];
    #pragma unroll
    for(int r=0;r<NR;r++){ v8[r] = pj*rwv[r]; v8[4+r] = wwj*rwv[r]; }
    #pragma unroll
    for(int q=0;q<8;q++){
      float s = waveSum(v8[q]);
      if(lane==0) s_pk[wv][q]=s;
    }
    __syncthreads();
    if (tid < 8){
      float ss=0;
      for(int w=0;w<16;w++) ss += s_pk[w][tid];
      scal[tid]=ss;
    }
    __syncthreads();
  }
  float dt[NR];
  #pragma unroll
  for(int r=0;r<NR;r++) dt[r] = dots[(b*5+r)*NM + j];
  float nrm = dots[(b*5+4)*NM + j];
  float inv = 1.0f/(sqrtf(nrm)+DELTA);
  float logit[NR], ce[NR], cw[NR];
  #pragma unroll
  for(int r=0;r<NR;r++) logit[r] = scal[12+r]*dt[r]*inv/(scal[8+r]+DELTA);
  #pragma unroll
  for(int r=0;r<NR;r++){
    float m1 = waveMax(logit[r]);
    if(lane==0) s_pk[wv][r]=m1;
  }
  __syncthreads();
  if (tid < NR){
    float mm=s_pk[0][tid];
    for(int w=1;w<16;w++) mm=fmaxf(mm,s_pk[w][tid]);
    smax[tid]=mm;
  }
  __syncthreads();
  #pragma unroll
  for(int r=0;r<NR;r++){
    ce[r] = expf(logit[r]-smax[r]);
    float s1 = waveSum(ce[r]);
    if(lane==0) s_pk[wv][r]=s1;
  }
  __syncthreads();
  if (tid < NR){
    float ss=0;
    for(int w=0;w<16;w++) ss += s_pk[w][tid];
    ssum[tid]=ss;
  }
  __syncthreads();
  #pragma unroll
  for(int r=0;r<NR;r++) cw[r] = ce[r]/ssum[r];
  float Ljj = ldiag[b*NM+j];
  float4 Fa = RFp4[(0<<16) + b*NM + j];
  float4 Fb = RFp4[(1<<16) + b*NM + j];
  float4 Fc = RFp4[(2<<16) + b*NM + j];
  float4 Fd = RFp4[(3<<16) + b*NM + j];
  float Fr[4] = {Fa.x+Fb.x+Fc.x+Fd.x, Fa.y+Fb.y+Fc.y+Fd.y,
                 Fa.z+Fb.z+Fc.z+Fd.z, Fa.w+Fb.w+Fc.w+Fd.w};
  #pragma unroll
  for(int r=0;r<NR;r++){
    int idx = (b*NR+r)*NM + j;
    float cc2 = C2p[idx] + C2p[262144+idx] + C2p[524288+idx] + C2p[786432+idx];
    float cc3 = C3p[idx] + C3p[262144+idx] + C3p[524288+idx] + C3p[786432+idx];
    float F   = Fr[r];
    float grj = rwv[r];
    float fwd = F - Ljj*grj*(1.0f-2.0f*wwj) + wwj*(scal[r] - pj*grj);
    float bwd = (cc2 - cc3) - Ljj*grj*(1.0f-wwj) - wwj*(cc2 - Ljj*grj) + pj*(scal[4+r] - wwj*grj);
    nrwg[(b*NR+r)*NM+j] = rm[r][0]*bwd + rm[r][1]*fwd + rm[r][2]*cw[r];
  }
}

// ---------------- K4c: read_vectors = nrw @ new_memory, 256-block partial matmul ----------------
__global__ __launch_bounds__(256) void k_readb(
    const float* __restrict__ iface, const float* __restrict__ mem,
    const float* __restrict__ wwp, const float* __restrict__ nrwg,
    float* __restrict__ out){
  int jt = blockIdx.x, b = blockIdx.y;
  int tid = threadIdx.x, lane = tid&63, wv = tid>>6;
  __shared__ float s_nrw[NR][256];
  __shared__ float s_ww[256];
  __shared__ float s_er[NW], s_wv[NW];
  __shared__ float s_acc[4][NR][NW];
  const float* ifb = iface + b*NIF;
  int j0 = jt*256;
  #pragma unroll
  for(int r=0;r<NR;r++) s_nrw[r][tid] = nrwg[(b*NR+r)*NM + j0+tid];
  s_ww[tid] = wwp[b*NM + j0+tid];
  if (tid < 64) s_er[tid] = sigmoidf_(ifb[325+tid]);
  else if (tid < 128) s_wv[tid-64] = ifb[389+tid-64];
  __syncthreads();
  int w = lane;
  float erw = s_er[w], wvw = s_wv[w];
  float acc[NR]={0,0,0,0};
  for(int jj=0;jj<64;jj++){
    int jl = wv*64+jj;
    float wwr = s_ww[jl];
    float nmv = fmaf(mem[((size_t)b*NM + j0+jl)*NW + w], (1.0f - wwr*erw), wwr*wvw);
    #pragma unroll
    for(int r=0;r<NR;r++) acc[r] = fmaf(s_nrw[r][jl], nmv, acc[r]);
  }
  #pragma unroll
  for(int r=0;r<NR;r++) s_acc[wv][r][w] = acc[r];
  __syncthreads();
  {
    int r = tid>>6, k = tid&63;
    float s = s_acc[0][r][k]+s_acc[1][r][k]+s_acc[2][r][k]+s_acc[3][r][k];
    atomicAdd(&out[b*NR*NW + r*NW + k], s);
  }
}

extern "C" void kernel_launch(void* const* d_in, const int* in_sizes, int n_in,
                              void* d_out, int out_size, void* d_ws, size_t ws_size,
                              hipStream_t stream) {
  (void)in_sizes; (void)n_in; (void)out_size; (void)ws_size;
  const float* xi   = (const float*)d_in[0];
  const float* Wm   = (const float*)d_in[1];
  const float* bW   = (const float*)d_in[2];
  const float* mem  = (const float*)d_in[3];
  const float* link = (const float*)d_in[4];
  const float* prec = (const float*)d_in[5];
  const float* rw   = (const float*)d_in[6];
  const float* wwo  = (const float*)d_in[7];
  const float* uv   = (const float*)d_in[8];
  float* out = (float*)d_out;
  float* ws  = (float*)d_ws;
  float* iface = ws;                  // 30208
  float* wwp   = ws + 30208;          // 65536
  float* uu    = ws + 95744;          // 65536
  float* wcd   = ws + 161280;         // 65536
  float* wcn   = ws + 226816;         // 65536
  float* dots  = ws + 292352;         // 327680 = [b][5][1024]
  float* ldiag = ws + 620032;         // 65536
  float* nrwg  = ws + 685568;         // 262144
  float* RFp   = ws + 947712;         // 4*262144 (4 slices, float4 [b][1024])
  float* C2p   = ws + 1996288;        // 4*262144
  float* C3p   = ws + 3044864;        // 4*262144
  k_iface<<<dim3(NB,2), 256, 0, stream>>>(xi, Wm, bW, iface);
  k_wcos <<<dim3(4,NB), 256, 0, stream>>>(iface, mem, rw, wwo, uv, uu, wcd, wcn);
  k_write2<<<NB, 1024, 0, stream>>>(iface, uu, wcd, wcn, wwp);
  k_linkr<<<dim3(4,5,NB), 256, 0, stream>>>(link, rw, wwp, RFp, C2p, C3p, ldiag,
                                            iface, mem, dots, (float4*)out);
  k_rmid <<<NB, 1024, 0, stream>>>(iface, prec, rw, wwp, dots, ldiag, (const float4*)RFp, C2p, C3p, nrwg);
  k_readb<<<dim3(4,NB), 256, 0, stream>>>(iface, mem, wwp, nrwg, out);
}

// Round 15
// 149.088 us; speedup vs baseline: 1.6156x; 1.0843x over previous
//
#include <hip/hip_runtime.h>

#define DELTA 1e-6f

// sizes: b=64, m=1024, w=64, r=4, d=512, iface=471
#define NB 64
#define NM 1024
#define NW 64
#define NR 4
#define ND 512
#define NIF 471

typedef unsigned long long ull;

__device__ __forceinline__ float sigmoidf_(float x){ return 1.0f/(1.0f+expf(-x)); }
__device__ __forceinline__ float softplusf_(float x){ return fmaxf(x,0.0f) + log1pf(expf(-fabsf(x))); }

__device__ __forceinline__ float waveSum(float v){
  #pragma unroll
  for(int o=32;o>0;o>>=1) v += __shfl_down(v,o,64);
  return v;
}
__device__ __forceinline__ float waveMax(float v){
  #pragma unroll
  for(int o=32;o>0;o>>=1) v = fmaxf(v, __shfl_down(v,o,64));
  return v;
}
__device__ __forceinline__ ull shflxor64(ull k, int m){
  unsigned lo = (unsigned)(k & 0xffffffffu), hi = (unsigned)(k>>32);
  lo = (unsigned)__shfl_xor((int)lo, m, 64);
  hi = (unsigned)__shfl_xor((int)hi, m, 64);
  return ((ull)hi<<32)|lo;
}

// ---------------- K1: iface = xi @ W + bW (128 blocks); half==0 blocks also zero `out` ----------------
__global__ __launch_bounds__(256) void k_iface(const float* __restrict__ xi,
                                               const float* __restrict__ Wm,
                                               const float* __restrict__ bW,
                                               float* __restrict__ iface,
                                               float4* __restrict__ out4){
  int b = blockIdx.x, half = blockIdx.y;
  __shared__ float xs[ND];
  if (half == 0 && threadIdx.x < 64) out4[b*64 + threadIdx.x] = make_float4(0.f,0.f,0.f,0.f);
  for(int k=threadIdx.x;k<ND;k+=256) xs[k]=xi[b*ND+k];
  __syncthreads();
  int c = half*236 + threadIdx.x;
  int cend = half ? NIF : 236;
  if (c < cend){
    float acc = bW[c];
    #pragma unroll 4
    for(int k=0;k<ND;k++) acc = fmaf(xs[k], Wm[k*NIF+c], acc);
    iface[b*NIF+c]=acc;
  }
}

// ---------------- K1b: full-GPU pass over mem for write-content dot/nrm + usage ----------------
__global__ __launch_bounds__(256) void k_wcos(
    const float* __restrict__ iface, const float* __restrict__ mem,
    const float* __restrict__ rw_old, const float* __restrict__ ww_old,
    const float* __restrict__ uv,
    float* __restrict__ uu, float* __restrict__ wcd, float* __restrict__ wcn){
  int b = blockIdx.y;
  int j = blockIdx.x*256 + threadIdx.x;
  __shared__ float wkey[NW];
  const float* ifb = iface + b*NIF;
  if (threadIdx.x < NW) wkey[threadIdx.x] = ifb[260+threadIdx.x];
  __syncthreads();
  float fg0=sigmoidf_(ifb[453]), fg1=sigmoidf_(ifb[454]);
  float fg2=sigmoidf_(ifb[455]), fg3=sigmoidf_(ifb[456]);
  float u0  = uv[b*NM+j];
  float wwo = ww_old[b*NM+j];
  float usage = u0 + (1.0f-u0)*wwo;
  float psi = (1.0f - fg0*rw_old[(b*NR+0)*NM+j])
            * (1.0f - fg1*rw_old[(b*NR+1)*NM+j])
            * (1.0f - fg2*rw_old[(b*NR+2)*NM+j])
            * (1.0f - fg3*rw_old[(b*NR+3)*NM+j]);
  usage *= psi;
  uu[b*NM+j] = DELTA + (1.0f-DELTA)*usage;
  float dot=0.0f, nrm=0.0f;
  const float4* mrow4 = (const float4*)(mem + ((size_t)b*NM + j)*NW);
  #pragma unroll 4
  for(int k=0;k<16;k++){
    float4 mv = mrow4[k];
    const float* wk = wkey + k*4;
    dot = fmaf(mv.x,wk[0],dot); dot = fmaf(mv.y,wk[1],dot);
    dot = fmaf(mv.z,wk[2],dot); dot = fmaf(mv.w,wk[3],dot);
    nrm = fmaf(mv.x,mv.x,nrm); nrm = fmaf(mv.y,mv.y,nrm);
    nrm = fmaf(mv.z,mv.z,nrm); nrm = fmaf(mv.w,mv.w,nrm);
  }
  wcd[b*NM+j]=dot; wcn[b*NM+j]=nrm;
}

// ---------------- K2: softmax + bitonic sort + cumprod + new_write_w (also zeroes sPK) ----------------
__global__ __launch_bounds__(1024) void k_write2(
    const float* __restrict__ iface, const float* __restrict__ uu,
    const float* __restrict__ wcd, const float* __restrict__ wcn,
    float* __restrict__ wwp, float* __restrict__ sPK){
  int b = blockIdx.x; int tid = threadIdx.x;
  int lane = tid & 63, wv = tid >> 6;
  __shared__ float wkey[NW];
  __shared__ ull skA[NM];
  __shared__ ull skB[NM];
  __shared__ float fb2[NM];
  __shared__ float red[17];
  __shared__ float s_wp[16], s_wp2[16];
  const float* ifb = iface + b*NIF;
  if (tid < NW) wkey[tid] = ifb[260+tid];
  if (tid < 16) sPK[b*16+tid] = 0.0f;   // zero the rdots2 atomic accumulators
  __syncthreads();
  float sw = softplusf_(1.0f + fmaxf(ifb[324],0.0f));
  float ag = sigmoidf_(ifb[457]);
  float wg = sigmoidf_(ifb[458]);
  float kn=0.0f;
  for(int k=0;k<NW;k++){ float t=wkey[k]; kn += t*t; }
  kn = sqrtf(kn);
  float logit = sw * wcd[b*NM+tid] / ((sqrtf(wcn[b*NM+tid])+DELTA)*(kn+DELTA));
  float m1 = waveMax(logit); if(lane==0) red[wv]=m1; __syncthreads();
  if(tid==0){ float mm=red[0]; for(int i=1;i<16;i++) mm=fmaxf(mm,red[i]); red[16]=mm; } __syncthreads();
  float e = expf(logit - red[16]);
  float s1 = waveSum(e); if(lane==0) red[wv]=s1; __syncthreads();
  if(tid==0){ float ss=0; for(int i=0;i<16;i++) ss+=red[i]; red[16]=ss; } __syncthreads();
  float wcw = e/red[16];
  float u = uu[b*NM+tid];
  ull k = ((ull)__float_as_uint(u) << 32) | (unsigned)tid;
  bool useA = true;
  for (int k2=2; k2<=NM; k2<<=1){
    for (int jj=k2>>1; jj>0; jj>>=1){
      ull p;
      if (jj >= 64){
        ull* buf = useA ? skA : skB;
        buf[tid] = k;
        __syncthreads();
        p = buf[tid^jj];
        useA = !useA;
      } else {
        p = shflxor64(k, jj);
      }
      bool lower = (tid & jj) == 0;
      bool asc   = (tid & k2) == 0;
      bool takeMin = (lower == asc);
      k = takeMin ? (k<p ? k : p) : (k>p ? k : p);
    }
  }
  float su = __uint_as_float((unsigned)(k>>32));
  int phi  = (int)(k & 0xffffffffu);
  float sc = su;
  #pragma unroll
  for (int off=1; off<64; off<<=1){
    float t = __shfl_up(sc, off, 64);
    if (lane >= off) sc *= t;
  }
  if (lane==63) s_wp[wv] = sc;
  __syncthreads();
  if (tid==0){
    float p=1.0f;
    for (int w=0;w<16;w++){ float t=s_wp[w]; s_wp2[w]=p; p*=t; }
  }
  __syncthreads();
  float P = sc * s_wp2[wv];
  float salloc = (1.0f - su)*P;
  fb2[phi] = salloc;
  __syncthreads();
  float alloc = fb2[tid];
  wwp[b*NM+tid] = wg*(ag*alloc + (1.0f-ag)*wcw);
}

// ---------------- K3: one streaming pass over L — EXACT round-11 k_link8 (measured 82us) ----------------
__global__ __launch_bounds__(256) void k_link8(
    const float* __restrict__ link, const float* __restrict__ rw,
    const float* __restrict__ wwp,
    float4* __restrict__ RFp, float* __restrict__ C2p, float* __restrict__ C3p,
    float* __restrict__ ldiag){
  int cx = blockIdx.x, ry = blockIdx.y, b = blockIdx.z;
  int tid = threadIdx.x, lane = tid&63, wv = tid>>6;
  __shared__ float4 s_L4[32*64];   // 32KB
  __shared__ float4 s_gcol4[256];  // 4KB {g0..g3} per col
  __shared__ float  s_mwc[256];    // 1KB: 1-ww[col]
  __shared__ float4 s_grow4[32];
  __shared__ float  s_wwr[32];
  __shared__ float4 s_rfp4[128];
  const float* Lb = link + ((size_t)b<<20);
  int colbase = cx*256, rowbase = ry*256;
  {
    float g0 = rw[(b*NR+0)*NM + colbase + tid];
    float g1 = rw[(b*NR+1)*NM + colbase + tid];
    float g2 = rw[(b*NR+2)*NM + colbase + tid];
    float g3 = rw[(b*NR+3)*NM + colbase + tid];
    s_gcol4[tid] = make_float4(g0,g1,g2,g3);
    s_mwc[tid] = 1.0f - wwp[b*NM + colbase + tid];
  }
  float c2a[NR][4], c3a[NR][4];
  #pragma unroll
  for(int r=0;r<NR;r++){
    #pragma unroll
    for(int e=0;e<4;e++){ c2a[r][e]=0.0f; c3a[r][e]=0.0f; }
  }
  for (int ch=0; ch<8; ++ch){
    int rb = rowbase + ch*32;
    if (tid < 128) ((float*)s_grow4)[tid] = rw[(b*NR+(tid&3))*NM + rb + (tid>>2)];
    if (tid < 32)  s_wwr[tid] = wwp[b*NM + rb + tid];
    #pragma unroll
    for (int jq=0;jq<8;jq++){
      int rl = wv + 4*jq;
      float4 lv = *(const float4*)(Lb + (size_t)(rb+rl)*NM + colbase + lane*4);
      s_L4[rl*64 + (lane ^ ((rl>>1)&7))] = lv;
    }
    __syncthreads();
    if (cx == ry && tid < 32){
      int coff = ch*32 + tid;
      float4 v = s_L4[tid*64 + ((coff>>2) ^ ((tid>>1)&7))];
      float d = (coff&1) ? ((coff&2)? v.w : v.y) : ((coff&2)? v.z : v.x);
      ldiag[b*NM + rb + tid] = d;
    }
    {
      int i5 = lane & 15, cg = lane >> 4;
      int rl0 = 2*i5;
      int sz = i5 & 7;
      float wwj0 = s_wwr[rl0], wwj1 = s_wwr[rl0+1];
      float rf0[4] = {0,0,0,0}, rf1[4] = {0,0,0,0};
      #pragma unroll
      for (int q=0;q<4;q++){
        int cq = wv*16 + cg*4 + q;
        float4 mw  = ((const float4*)s_mwc)[cq];
        float4 lv0 = s_L4[rl0*64 + (cq ^ sz)];
        float4 lv1 = s_L4[(rl0+1)*64 + (cq ^ sz)];
        float le0[4]={lv0.x,lv0.y,lv0.z,lv0.w};
        float le1[4]={lv1.x,lv1.y,lv1.z,lv1.w};
        float mv[4]={mw.x,mw.y,mw.z,mw.w};
        #pragma unroll
        for (int e=0;e<4;e++){
          float4 gv = s_gcol4[cq*4+e];
          float lt0 = le0[e]*(mv[e]-wwj0);
          float lt1 = le1[e]*(mv[e]-wwj1);
          rf0[0]=fmaf(lt0,gv.x,rf0[0]); rf0[1]=fmaf(lt0,gv.y,rf0[1]);
          rf0[2]=fmaf(lt0,gv.z,rf0[2]); rf0[3]=fmaf(lt0,gv.w,rf0[3]);
          rf1[0]=fmaf(lt1,gv.x,rf1[0]); rf1[1]=fmaf(lt1,gv.y,rf1[1]);
          rf1[2]=fmaf(lt1,gv.z,rf1[2]); rf1[3]=fmaf(lt1,gv.w,rf1[3]);
        }
      }
      #pragma unroll
      for (int r=0;r<NR;r++){
        rf0[r] += __shfl_xor(rf0[r], 16, 64);
        rf0[r] += __shfl_xor(rf0[r], 32, 64);
        rf1[r] += __shfl_xor(rf1[r], 16, 64);
        rf1[r] += __shfl_xor(rf1[r], 32, 64);
      }
      if (cg == 0){
        s_rfp4[wv*32 + rl0]     = make_float4(rf0[0],rf0[1],rf0[2],rf0[3]);
        s_rfp4[wv*32 + rl0 + 1] = make_float4(rf1[0],rf1[1],rf1[2],rf1[3]);
      }
    }
    #pragma unroll 2
    for (int ri=0; ri<8; ri++){
      int row = wv*8 + ri;
      float4 lv = s_L4[row*64 + (lane ^ ((row>>1)&7))];
      float4 gg = s_grow4[row];
      float wwr = s_wwr[row];
      float le[4] = {lv.x,lv.y,lv.z,lv.w};
      float ggv[4] = {gg.x,gg.y,gg.z,gg.w};
      float ggw[4];
      #pragma unroll
      for (int r=0;r<NR;r++) ggw[r] = ggv[r]*wwr;
      #pragma unroll
      for (int e=0;e<4;e++){
        #pragma unroll
        for (int r=0;r<NR;r++){
          c2a[r][e] = fmaf(le[e], ggv[r], c2a[r][e]);
          c3a[r][e] = fmaf(le[e], ggw[r], c3a[r][e]);
        }
      }
    }
    __syncthreads();
    if (tid < 128){
      int row = tid>>2, r = tid&3;
      float s = ((const float*)&s_rfp4[0*32+row])[r] + ((const float*)&s_rfp4[1*32+row])[r]
              + ((const float*)&s_rfp4[2*32+row])[r] + ((const float*)&s_rfp4[3*32+row])[r];
      ((float*)RFp)[((size_t)cx<<18) + (b*NM + rb + row)*4 + r] = s;
    }
    __syncthreads();
  }
  float4* s_comb = s_L4;
  #pragma unroll
  for (int r=0;r<NR;r++){
    s_comb[tid*8 + r]     = make_float4(c2a[r][0],c2a[r][1],c2a[r][2],c2a[r][3]);
    s_comb[tid*8 + 4 + r] = make_float4(c3a[r][0],c3a[r][1],c3a[r][2],c3a[r][3]);
  }
  __syncthreads();
  for (int t=tid; t<512; t+=256){
    int lc = t>>3, q = t&7;
    float4 a = s_comb[(0*64+lc)*8+q];
    float4 bb= s_comb[(1*64+lc)*8+q];
    float4 c = s_comb[(2*64+lc)*8+q];
    float4 d = s_comb[(3*64+lc)*8+q];
    float4 s = make_float4(a.x+bb.x+c.x+d.x, a.y+bb.y+c.y+d.y, a.z+bb.z+c.z+d.z, a.w+bb.w+c.w+d.w);
    float* dst = (q<4) ? &C2p[((size_t)ry<<18) + (b*NR+q)*NM + colbase + lc*4]
                       : &C3p[((size_t)ry<<18) + (b*NR+(q-4))*NM + colbase + lc*4];
    *(float4*)dst = s;
  }
}

// ---------------- K4a: mem pass -> ce = exp(read logit) + block partials of Pr/Kr/sumexp ----------------
// Softmax without max-subtraction: logit = strength*cosine, |logit| <= ~7 -> exp in [1e-3, 8e2],
// sums <= 8e5: fp32-safe; cw = ce/sum identical to the max-subtracted form up to rounding.
__global__ __launch_bounds__(256) void k_rdots2(
    const float* __restrict__ iface, const float* __restrict__ mem,
    const float* __restrict__ wwp, const float* __restrict__ prec,
    const float* __restrict__ rw_old,
    float* __restrict__ ce, float* __restrict__ sPK){
  int b = blockIdx.y, jt = blockIdx.x;
  int tid = threadIdx.x, lane = tid&63, wv = tid>>6;
  __shared__ float keys[NR][NW];
  __shared__ float er[NW], wvec[NW];
  __shared__ float sk[NR];
  __shared__ float red[4][12];
  const float* ifb = iface + b*NIF;
  { int r=tid>>6, kk=tid&63; keys[r][kk] = ifb[r*NW+kk]; }
  if (tid < 64) er[tid] = sigmoidf_(ifb[325+tid]);
  else if (tid < 128) wvec[tid-64] = ifb[389+tid-64];
  else if (tid < 132){
    int r = tid-128;
    float knv=0;
    for(int k=0;k<NW;k++){ float t=ifb[r*NW+k]; knv += t*t; }
    sk[r] = softplusf_(1.0f + fmaxf(ifb[256+r],0.0f)) / (sqrtf(knv)+DELTA);
  }
  __syncthreads();
  int j = jt*256 + tid;
  float wwj = wwp[b*NM+j];
  float pj  = prec[b*NM+j];
  const float* mrow = mem + ((size_t)b*NM+j)*NW;
  float dt[NR]={0,0,0,0}; float nrm=0.0f;
  for(int k=0;k<NW;k++){
    float nmv = fmaf(mrow[k], (1.0f - wwj*er[k]), wwj*wvec[k]);
    nrm = fmaf(nmv,nmv,nrm);
    #pragma unroll
    for(int r=0;r<NR;r++) dt[r] = fmaf(nmv, keys[r][k], dt[r]);
  }
  float inv = 1.0f/(sqrtf(nrm)+DELTA);
  float v12[12];
  #pragma unroll
  for(int r=0;r<NR;r++){
    float e = expf(sk[r]*dt[r]*inv);
    ce[(b*NR+r)*NM + j] = e;
    float rwv = rw_old[(b*NR+r)*NM+j];
    v12[r]   = pj*rwv;    // Pr partial
    v12[4+r] = wwj*rwv;   // Kr partial
    v12[8+r] = e;         // sum-exp partial
  }
  #pragma unroll
  for(int q=0;q<12;q++){
    float s = waveSum(v12[q]);
    if (lane==0) red[wv][q] = s;
  }
  __syncthreads();
  if (tid < 12){
    float s = red[0][tid]+red[1][tid]+red[2][tid]+red[3][tid];
    atomicAdd(&sPK[b*16+tid], s);
  }
}

// ---------------- K4b: fused finalize (nrw inline) + read_vectors partial matmul ----------------
__global__ __launch_bounds__(256) void k_readf(
    const float* __restrict__ iface, const float* __restrict__ mem,
    const float* __restrict__ wwp, const float* __restrict__ prec,
    const float* __restrict__ rw_old, const float* __restrict__ ldiag,
    const float4* __restrict__ RFp4, const float* __restrict__ C2p, const float* __restrict__ C3p,
    const float* __restrict__ ce, const float* __restrict__ sPK,
    float* __restrict__ out){
  int jt = blockIdx.x, b = blockIdx.y;
  int tid = threadIdx.x, lane = tid&63, wv = tid>>6;
  __shared__ float s_nrw[NR][256];
  __shared__ float s_ww[256];
  __shared__ float s_er[NW], s_wv[NW];
  __shared__ float s_acc[4][NR][NW];
  __shared__ float rm[NR][3];
  __shared__ float s_sc[16];   // [0..3]=Pr, [4..7]=Kr, [8..11]=sumexp
  const float* ifb = iface + b*NIF;
  if (tid == 0){
    for(int mo=0;mo<3;mo++){
      float x0=ifb[458+0*3+mo], x1=ifb[458+1*3+mo], x2=ifb[458+2*3+mo], x3=ifb[458+3*3+mo];
      float mx = fmaxf(fmaxf(x0,x1),fmaxf(x2,x3));
      float e0=expf(x0-mx),e1=expf(x1-mx),e2=expf(x2-mx),e3=expf(x3-mx);
      float s=e0+e1+e2+e3;
      rm[0][mo]=e0/s; rm[1][mo]=e1/s; rm[2][mo]=e2/s; rm[3][mo]=e3/s;
    }
  }
  if (tid >= 64 && tid < 80)  s_sc[tid-64] = sPK[b*16 + (tid-64)];
  if (tid >= 128 && tid < 192) s_er[tid-128] = sigmoidf_(ifb[325+tid-128]);
  if (tid >= 192)              s_wv[tid-192] = ifb[389+tid-192];
  int j0 = jt*256;
  int j = j0 + tid;
  float wwj = wwp[b*NM+j];
  s_ww[tid] = wwj;
  __syncthreads();
  float pj  = prec[b*NM+j];
  float Ljj = ldiag[b*NM+j];
  float4 Fa = RFp4[(0<<16) + b*NM + j];
  float4 Fb = RFp4[(1<<16) + b*NM + j];
  float4 Fc = RFp4[(2<<16) + b*NM + j];
  float4 Fd = RFp4[(3<<16) + b*NM + j];
  float Fr[4] = {Fa.x+Fb.x+Fc.x+Fd.x, Fa.y+Fb.y+Fc.y+Fd.y,
                 Fa.z+Fb.z+Fc.z+Fd.z, Fa.w+Fb.w+Fc.w+Fd.w};
  #pragma unroll
  for(int r=0;r<NR;r++){
    int idx = (b*NR+r)*NM + j;
    float cc2 = C2p[idx] + C2p[262144+idx] + C2p[524288+idx] + C2p[786432+idx];
    float cc3 = C3p[idx] + C3p[262144+idx] + C3p[524288+idx] + C3p[786432+idx];
    float grj = rw_old[idx];
    float cwv = ce[idx] / s_sc[8+r];
    float fwd = Fr[r] - Ljj*grj*(1.0f-2.0f*wwj) + wwj*(s_sc[r] - pj*grj);
    float bwd = (cc2 - cc3) - Ljj*grj*(1.0f-wwj) - wwj*(cc2 - Ljj*grj) + pj*(s_sc[4+r] - wwj*grj);
    s_nrw[r][tid] = rm[r][0]*bwd + rm[r][1]*fwd + rm[r][2]*cwv;
  }
  __syncthreads();
  int w = lane;
  float erw = s_er[w], wvw = s_wv[w];
  float acc[NR]={0,0,0,0};
  for(int jj=0;jj<64;jj++){
    int jl = wv*64+jj;
    float wwr = s_ww[jl];
    float nmv = fmaf(mem[((size_t)b*NM + j0+jl)*NW + w], (1.0f - wwr*erw), wwr*wvw);
    #pragma unroll
    for(int r=0;r<NR;r++) acc[r] = fmaf(s_nrw[r][jl], nmv, acc[r]);
  }
  #pragma unroll
  for(int r=0;r<NR;r++) s_acc[wv][r][w] = acc[r];
  __syncthreads();
  {
    int r = tid>>6, k = tid&63;
    float s = s_acc[0][r][k]+s_acc[1][r][k]+s_acc[2][r][k]+s_acc[3][r][k];
    atomicAdd(&out[b*NR*NW + r*NW + k], s);
  }
}

extern "C" void kernel_launch(void* const* d_in, const int* in_sizes, int n_in,
                              void* d_out, int out_size, void* d_ws, size_t ws_size,
                              hipStream_t stream) {
  (void)in_sizes; (void)n_in; (void)out_size; (void)ws_size;
  const float* xi   = (const float*)d_in[0];
  const float* Wm   = (const float*)d_in[1];
  const float* bW   = (const float*)d_in[2];
  const float* mem  = (const float*)d_in[3];
  const float* link = (const float*)d_in[4];
  const float* prec = (const float*)d_in[5];
  const float* rw   = (const float*)d_in[6];
  const float* wwo  = (const float*)d_in[7];
  const float* uv   = (const float*)d_in[8];
  float* out = (float*)d_out;
  float* ws  = (float*)d_ws;
  float* iface = ws;                  // 30208
  float* wwp   = ws + 30208;          // 65536
  float* uu    = ws + 95744;          // 65536
  float* wcd   = ws + 161280;         // 65536
  float* wcn   = ws + 226816;         // 65536
  float* ce    = ws + 292352;         // 262144 = [b][4][1024]
  float* ldiag = ws + 554496;         // 65536
  float* sPK   = ws + 620032;         // 1024 = [b][16]
  float* RFp   = ws + 621056;         // 4*262144 (float4-aligned)
  float* C2p   = ws + 1669632;        // 4*262144
  float* C3p   = ws + 2718208;        // 4*262144
  k_iface<<<dim3(NB,2), 256, 0, stream>>>(xi, Wm, bW, iface, (float4*)out);
  k_wcos <<<dim3(4,NB), 256, 0, stream>>>(iface, mem, rw, wwo, uv, uu, wcd, wcn);
  k_write2<<<NB, 1024, 0, stream>>>(iface, uu, wcd, wcn, wwp, sPK);
  k_link8<<<dim3(4,4,NB), 256, 0, stream>>>(link, rw, wwp, (float4*)RFp, C2p, C3p, ldiag);
  k_rdots2<<<dim3(4,NB), 256, 0, stream>>>(iface, mem, wwp, prec, rw, ce, sPK);
  k_readf<<<dim3(4,NB), 256, 0, stream>>>(iface, mem, wwp, prec, rw, ldiag,
                                          (const float4*)RFp, C2p, C3p, ce, sPK, out);
}